// Round 1
// baseline (996.822 us; speedup 1.0000x reference)
//
#include <hip/hip_runtime.h>
#include <cfloat>
#include <cmath>

#define NPT   1024          // points per cloud
#define NCL   32            // clouds (B*S)
#define PTOT  32768         // total points
#define HH    64
#define KNN_K 16

__device__ __forceinline__ float wave_sum64(float t) {
#pragma unroll
  for (int o = 32; o > 0; o >>= 1) t += __shfl_xor(t, o, 64);
  return t;
}

__device__ __forceinline__ float gelu_f(float x) {
  float x3 = x * x * x;
  return 0.5f * x * (1.0f + tanhf(0.7978845608028654f * (x + 0.044715f * x3)));
}

// ---------------- K0: input projection + pos extract -----------------------
__global__ void k_inproj(const float* __restrict__ pts,
                         const float* __restrict__ w_in,
                         const float* __restrict__ b_in,
                         float* __restrict__ x, float* __restrict__ pos) {
  int p = blockIdx.x * 4 + (threadIdx.x >> 6);
  int h = threadIdx.x & 63;
  const float* pp = pts + p * 6;
  float acc = b_in[h];
#pragma unroll
  for (int f = 0; f < 6; ++f) acc += pp[f] * w_in[f * HH + h];
  x[p * HH + h] = acc;
  if (h < 3) pos[p * 3 + h] = pp[h];
}

// ---------------- K1: 16-NN per point (once; pos constant over layers) -----
__global__ __launch_bounds__(256) void k_knn(const float* __restrict__ pos,
                                             int* __restrict__ nidx) {
  __shared__ float sx[NPT], sy[NPT], sz[NPT];
  int cloud = blockIdx.x;
  const float* cp = pos + cloud * NPT * 3;
  for (int j = threadIdx.x; j < NPT; j += 256) {
    sx[j] = cp[j * 3 + 0];
    sy[j] = cp[j * 3 + 1];
    sz[j] = cp[j * 3 + 2];
  }
  __syncthreads();
  int i = blockIdx.y * 256 + threadIdx.x;
  float qx = sx[i], qy = sy[i], qz = sz[i];

  float bd[KNN_K];
  int bi[KNN_K];
#pragma unroll
  for (int k = 0; k < KNN_K; ++k) { bd[k] = FLT_MAX; bi[k] = 0; }

  for (int j = 0; j < NPT; ++j) {
    float dx = qx - sx[j], dy = qy - sy[j], dz = qz - sz[j];
    // exact IEEE, reference order: (dx*dx + dy*dy) + dz*dz, no fma contraction
    float d2 = __fadd_rn(__fadd_rn(__fmul_rn(dx, dx), __fmul_rn(dy, dy)),
                         __fmul_rn(dz, dz));
    if (d2 < bd[KNN_K - 1]) {          // ties rejected -> lower index kept
      bd[KNN_K - 1] = d2; bi[KNN_K - 1] = j;
#pragma unroll
      for (int k = KNN_K - 1; k > 0; --k) {
        if (bd[k] < bd[k - 1]) {       // strict -> stable (lower index first)
          float td = bd[k]; bd[k] = bd[k - 1]; bd[k - 1] = td;
          int   ti = bi[k]; bi[k] = bi[k - 1]; bi[k - 1] = ti;
        }
      }
    }
  }
  int base = (cloud * NPT + i) * KNN_K;
#pragma unroll
  for (int k = 0; k < KNN_K; ++k) nidx[base + k] = bi[k];
}

// ---------------- K2: per-layer q,k,v projections ---------------------------
__global__ void k_qkv(const float* __restrict__ x,
                      const float* __restrict__ Wq, const float* __restrict__ bq,
                      const float* __restrict__ Wk, const float* __restrict__ bk,
                      const float* __restrict__ Wv, const float* __restrict__ bv,
                      float* __restrict__ q, float* __restrict__ k,
                      float* __restrict__ v) {
  int p = blockIdx.x * 4 + (threadIdx.x >> 6);
  int h = threadIdx.x & 63;
  const float* xr = x + p * HH;
  float aq = bq[h], ak = bk[h], av = bv[h];
#pragma unroll 8
  for (int g = 0; g < HH; ++g) {
    float xv = xr[g];
    aq += xv * Wq[g * HH + h];
    ak += xv * Wk[g * HH + h];
    av += xv * Wv[g * HH + h];
  }
  q[p * HH + h] = aq;
  k[p * HH + h] = ak;
  v[p * HH + h] = av;
}

// ---------------- K3: fused neighbor attention + Wo + gelu + residual + LN --
__global__ void k_attn(float* __restrict__ x, const float* __restrict__ pos,
                       const int* __restrict__ nidx,
                       const float* __restrict__ qb, const float* __restrict__ kb,
                       const float* __restrict__ vb,
                       const float* __restrict__ Wpe, const float* __restrict__ bpe,
                       const float* __restrict__ Wpd, const float* __restrict__ bpd,
                       const float* __restrict__ Wa, const float* __restrict__ ba,
                       const float* __restrict__ Wo, const float* __restrict__ bo,
                       const float* __restrict__ ln_s, const float* __restrict__ ln_b) {
  int p = blockIdx.x * 4 + (threadIdx.x >> 6);
  int lane = threadIdx.x & 63;
  int cbase = p & ~(NPT - 1);     // first point of this cloud

  float px = pos[p * 3 + 0], py = pos[p * 3 + 1], pz = pos[p * 3 + 2];
  float wpe0 = Wpe[0 * HH + lane], wpe1 = Wpe[1 * HH + lane], wpe2 = Wpe[2 * HH + lane];
  float wpd0 = Wpd[0 * HH + lane], wpd1 = Wpd[1 * HH + lane], wpd2 = Wpd[2 * HH + lane];
  float bpeh = bpe[lane], bpdh = bpd[lane];

  float pe_i = bpeh + px * wpe0 + py * wpe1 + pz * wpe2;
  float qp = qb[p * HH + lane] + pe_i;
  float wa = Wa[lane];
  float ba0 = ba[0];

  const int* ni = nidx + p * KNN_K;
  float vj[KNN_K], logit[KNN_K];

#pragma unroll
  for (int jj = 0; jj < KNN_K; ++jj) {
    int g = cbase + ni[jj];
    float kv = kb[g * HH + lane];
    vj[jj] = vb[g * HH + lane];
    float jx = pos[g * 3 + 0], jy = pos[g * 3 + 1], jz = pos[g * 3 + 2];
    float pe_j = bpeh + jx * wpe0 + jy * wpe1 + jz * wpe2;
    float pd = bpdh + (jx - px) * wpd0 + (jy - py) * wpd1 + (jz - pz) * wpd2;
    float t = qp * (kv + pe_j + pd) * 0.125f * wa;
    logit[jj] = wave_sum64(t) + ba0;
  }

  // softmax over 16 (replicated across lanes)
  float m = logit[0];
#pragma unroll
  for (int jj = 1; jj < KNN_K; ++jj) m = fmaxf(m, logit[jj]);
  float s = 0.f;
#pragma unroll
  for (int jj = 0; jj < KNN_K; ++jj) { logit[jj] = expf(logit[jj] - m); s += logit[jj]; }
  float out = 0.f;
#pragma unroll
  for (int jj = 0; jj < KNN_K; ++jj) out += (logit[jj] / s) * vj[jj];

  // y = gelu(out @ Wo + bo)
  float y = bo[lane];
#pragma unroll 8
  for (int g = 0; g < HH; ++g) {
    float og = __shfl(out, g, 64);
    y += og * Wo[g * HH + lane];
  }
  y = gelu_f(y);

  // residual + layernorm
  float xn = x[p * HH + lane] + y;
  float mu = wave_sum64(xn) * (1.0f / HH);
  float d = xn - mu;
  float var = wave_sum64(d * d) * (1.0f / HH);
  float r = rsqrtf(var + 1e-6f);
  x[p * HH + lane] = d * r * ln_s[lane] + ln_b[lane];
}

// ---------------- K4: max over N -------------------------------------------
__global__ void k_pool(const float* __restrict__ x, float* __restrict__ pooled) {
  __shared__ float red[4][HH];
  int bs = blockIdx.x;
  int h = threadIdx.x & 63;
  int c = threadIdx.x >> 6;
  const float* xp = x + bs * NPT * HH;
  float m = -FLT_MAX;
  for (int n = c; n < NPT; n += 4) m = fmaxf(m, xp[n * HH + h]);
  red[c][h] = m;
  __syncthreads();
  if (c == 0) {
    m = fmaxf(fmaxf(red[0][h], red[1][h]), fmaxf(red[2][h], red[3][h]));
    pooled[bs * HH + h] = m;
  }
}

// ---------------- K5: set-encoder layer + final LN + max over S -------------
__global__ __launch_bounds__(512) void k_enc(
    const float* __restrict__ pooled,
    const float* __restrict__ Wek, const float* __restrict__ bek,
    const float* __restrict__ Weq, const float* __restrict__ beq,
    const float* __restrict__ Wev, const float* __restrict__ bev,
    const float* __restrict__ We1, const float* __restrict__ be1,
    const float* __restrict__ We2, const float* __restrict__ be2,
    const float* __restrict__ ln2_s, const float* __restrict__ ln2_b,
    float* __restrict__ out) {
  __shared__ float xs[8][HH], ks[8][HH], vs[8][HH], x2[8][HH];
  int b = blockIdx.x;
  int t = threadIdx.x >> 6;     // token 0..7
  int h = threadIdx.x & 63;
  const float* xp = pooled + b * 8 * HH;
  xs[t][h] = xp[t * HH + h];
  __syncthreads();

  float kk = bek[h], qq = beq[h], vv = bev[h];
#pragma unroll 8
  for (int g = 0; g < HH; ++g) {
    float xv = xs[t][g];
    kk += xv * Wek[g * HH + h];
    qq += xv * Weq[g * HH + h];
    vv += xv * Wev[g * HH + h];
  }
  ks[t][h] = kk;
  vs[t][h] = vv;
  __syncthreads();

  float logit[8];
#pragma unroll
  for (int s = 0; s < 8; ++s) {
    float tt = qq * ks[s][h];
    logit[s] = wave_sum64(tt) * 0.125f;
  }
  float m = logit[0];
#pragma unroll
  for (int s = 1; s < 8; ++s) m = fmaxf(m, logit[s]);
  float ssum = 0.f;
#pragma unroll
  for (int s = 0; s < 8; ++s) { logit[s] = expf(logit[s] - m); ssum += logit[s]; }
  float o = 0.f;
#pragma unroll
  for (int s = 0; s < 8; ++s) o += (logit[s] / ssum) * vs[s][h];

  float h1 = be1[h];
#pragma unroll 8
  for (int g = 0; g < HH; ++g) h1 += __shfl(o, g, 64) * We1[g * HH + h];
  h1 = gelu_f(h1);
  float h2 = be2[h];
#pragma unroll 8
  for (int g = 0; g < HH; ++g) h2 += __shfl(h1, g, 64) * We2[g * HH + h];

  float xn = xs[t][h] + h2;
  float mu = wave_sum64(xn) * (1.0f / HH);
  float d = xn - mu;
  float var = wave_sum64(d * d) * (1.0f / HH);
  float yv = d * rsqrtf(var + 1e-6f) * ln2_s[h] + ln2_b[h];
  x2[t][h] = yv;
  __syncthreads();
  if (t == 0) {
    float mm = x2[0][h];
#pragma unroll
    for (int s = 1; s < 8; ++s) mm = fmaxf(mm, x2[s][h]);
    out[b * HH + h] = mm;
  }
}

// ---------------------------------------------------------------------------
extern "C" void kernel_launch(void* const* d_in, const int* in_sizes, int n_in,
                              void* d_out, int out_size, void* d_ws, size_t ws_size,
                              hipStream_t stream) {
  const float* points = (const float*)d_in[0];
  const float* w_in   = (const float*)d_in[1];
  const float* b_in   = (const float*)d_in[2];
  const float* Wq     = (const float*)d_in[3];
  const float* bq     = (const float*)d_in[4];
  const float* Wk     = (const float*)d_in[5];
  const float* bk     = (const float*)d_in[6];
  const float* Wv     = (const float*)d_in[7];
  const float* bv     = (const float*)d_in[8];
  const float* Wpe    = (const float*)d_in[9];
  const float* bpe    = (const float*)d_in[10];
  const float* Wpd    = (const float*)d_in[11];
  const float* bpd    = (const float*)d_in[12];
  const float* Wa     = (const float*)d_in[13];
  const float* ba     = (const float*)d_in[14];
  const float* Wo     = (const float*)d_in[15];
  const float* bo     = (const float*)d_in[16];
  const float* ln_s   = (const float*)d_in[17];
  const float* ln_b   = (const float*)d_in[18];
  const float* Wek    = (const float*)d_in[19];
  const float* bek    = (const float*)d_in[20];
  const float* Weq    = (const float*)d_in[21];
  const float* beq    = (const float*)d_in[22];
  const float* Wev    = (const float*)d_in[23];
  const float* bev    = (const float*)d_in[24];
  const float* We1    = (const float*)d_in[25];
  const float* be1    = (const float*)d_in[26];
  const float* We2    = (const float*)d_in[27];
  const float* be2    = (const float*)d_in[28];
  const float* ln2_s  = (const float*)d_in[29];
  const float* ln2_b  = (const float*)d_in[30];

  float* ws     = (float*)d_ws;
  float* pos    = ws;                     // 3*PTOT
  float* xbuf   = pos  + 3 * PTOT;        // 64*PTOT
  float* qbuf   = xbuf + 64 * PTOT;
  float* kbuf   = qbuf + 64 * PTOT;
  float* vbuf   = kbuf + 64 * PTOT;
  float* pooled = vbuf + 64 * PTOT;       // 32*64
  int*   nidx   = (int*)(pooled + NCL * HH);  // 16*PTOT ints

  k_inproj<<<PTOT / 4, 256, 0, stream>>>(points, w_in, b_in, xbuf, pos);
  k_knn<<<dim3(NCL, 4), 256, 0, stream>>>(pos, nidx);

  for (int l = 0; l < 3; ++l) {
    k_qkv<<<PTOT / 4, 256, 0, stream>>>(xbuf,
        Wq + l * HH * HH, bq + l * HH,
        Wk + l * HH * HH, bk + l * HH,
        Wv + l * HH * HH, bv + l * HH,
        qbuf, kbuf, vbuf);
    k_attn<<<PTOT / 4, 256, 0, stream>>>(xbuf, pos, nidx, qbuf, kbuf, vbuf,
        Wpe + l * 3 * HH, bpe + l * HH,
        Wpd + l * 3 * HH, bpd + l * HH,
        Wa + l * HH, ba + l,
        Wo + l * HH * HH, bo + l * HH,
        ln_s + l * HH, ln_b + l * HH);
  }

  k_pool<<<NCL, 256, 0, stream>>>(xbuf, pooled);
  k_enc<<<4, 512, 0, stream>>>(pooled, Wek, bek, Weq, beq, Wev, bev,
                               We1, be1, We2, be2, ln2_s, ln2_b, (float*)d_out);
}

// Round 2
// 580.247 us; speedup vs baseline: 1.7179x; 1.7179x over previous
//
#include <hip/hip_runtime.h>
#include <cfloat>
#include <cmath>

#define NPT   1024          // points per cloud
#define NCL   32            // clouds (B*S)
#define PTOT  32768         // total points
#define HH    64
#define KNN_K 16

__device__ __forceinline__ float wave_sum64(float t) {
#pragma unroll
  for (int o = 32; o > 0; o >>= 1) t += __shfl_xor(t, o, 64);
  return t;
}

__device__ __forceinline__ float gelu_f(float x) {
  float x3 = x * x * x;
  return 0.5f * x * (1.0f + tanhf(0.7978845608028654f * (x + 0.044715f * x3)));
}

// ---------------- K0: input projection + pos extract -----------------------
__global__ void k_inproj(const float* __restrict__ pts,
                         const float* __restrict__ w_in,
                         const float* __restrict__ b_in,
                         float* __restrict__ x, float* __restrict__ pos) {
  int p = blockIdx.x * 4 + (threadIdx.x >> 6);
  int h = threadIdx.x & 63;
  const float* pp = pts + p * 6;
  float acc = b_in[h];
#pragma unroll
  for (int f = 0; f < 6; ++f) acc += pp[f] * w_in[f * HH + h];
  x[p * HH + h] = acc;
  if (h < 3) pos[p * 3 + h] = pp[h];
}

// ---------------- K1: 16-NN, one wave per query point ----------------------
// Lane l owns candidates j = c*64 + l for c in 0..15. 16 extract-min rounds,
// exact jax.lax.top_k tie semantics (stable: equal distance -> lower index).
__global__ __launch_bounds__(256) void k_knn(const float* __restrict__ pos,
                                             int* __restrict__ nidx) {
  __shared__ float sx[NPT], sy[NPT], sz[NPT];
  int cloud = blockIdx.x >> 8;            // 256 blocks per cloud
  int qbase = (blockIdx.x & 255) * 4;     // 4 queries (waves) per block
  const float* cp = pos + cloud * NPT * 3;
  for (int j = threadIdx.x; j < NPT; j += 256) {
    sx[j] = cp[j * 3 + 0];
    sy[j] = cp[j * 3 + 1];
    sz[j] = cp[j * 3 + 2];
  }
  __syncthreads();

  int wv = threadIdx.x >> 6;
  int lane = threadIdx.x & 63;
  int i = qbase + wv;                     // query index within cloud
  float qx = sx[i], qy = sy[i], qz = sz[i];

  float d[16];
#pragma unroll
  for (int c = 0; c < 16; ++c) {
    int j = c * 64 + lane;
    float dx = qx - sx[j], dy = qy - sy[j], dz = qz - sz[j];
    // exact IEEE, reference order: (dx*dx + dy*dy) + dz*dz, no fma contraction
    d[c] = __fadd_rn(__fadd_rn(__fmul_rn(dx, dx), __fmul_rn(dy, dy)),
                     __fmul_rn(dz, dz));
  }

  int obase = (cloud * NPT + i) * KNN_K;
  for (int r = 0; r < KNN_K; ++r) {
    // local min over my 16 (strict < ascending -> lowest chunk on ties)
    float bd = d[0];
    int bc = 0;
#pragma unroll
    for (int c = 1; c < 16; ++c) {
      if (d[c] < bd) { bd = d[c]; bc = c; }
    }
    // wave min distance
    float gd = bd;
#pragma unroll
    for (int o = 32; o > 0; o >>= 1) gd = fminf(gd, __shfl_xor(gd, o, 64));
    // among distance-tied lanes, lowest candidate index wins (top_k stability)
    int myidx = bc * 64 + lane;
    int cand = (bd == gd) ? myidx : 0x7fffffff;
    int gidx = cand;
#pragma unroll
    for (int o = 32; o > 0; o >>= 1) gidx = min(gidx, __shfl_xor(gidx, o, 64));
    if (lane == 0) nidx[obase + r] = gidx;
    // remove the winner (static indices only — no scratch spill)
    bool win = (myidx == gidx);
#pragma unroll
    for (int c = 0; c < 16; ++c) {
      d[c] = (win && c == bc) ? FLT_MAX : d[c];
    }
  }
}

// ---------------- K2: per-layer q,k,v projections ---------------------------
__global__ void k_qkv(const float* __restrict__ x,
                      const float* __restrict__ Wq, const float* __restrict__ bq,
                      const float* __restrict__ Wk, const float* __restrict__ bk,
                      const float* __restrict__ Wv, const float* __restrict__ bv,
                      float* __restrict__ q, float* __restrict__ k,
                      float* __restrict__ v) {
  int p = blockIdx.x * 4 + (threadIdx.x >> 6);
  int h = threadIdx.x & 63;
  const float* xr = x + p * HH;
  float aq = bq[h], ak = bk[h], av = bv[h];
#pragma unroll 8
  for (int g = 0; g < HH; ++g) {
    float xv = xr[g];
    aq += xv * Wq[g * HH + h];
    ak += xv * Wk[g * HH + h];
    av += xv * Wv[g * HH + h];
  }
  q[p * HH + h] = aq;
  k[p * HH + h] = ak;
  v[p * HH + h] = av;
}

// ---------------- K3: fused neighbor attention + Wo + gelu + residual + LN --
__global__ void k_attn(float* __restrict__ x, const float* __restrict__ pos,
                       const int* __restrict__ nidx,
                       const float* __restrict__ qb, const float* __restrict__ kb,
                       const float* __restrict__ vb,
                       const float* __restrict__ Wpe, const float* __restrict__ bpe,
                       const float* __restrict__ Wpd, const float* __restrict__ bpd,
                       const float* __restrict__ Wa, const float* __restrict__ ba,
                       const float* __restrict__ Wo, const float* __restrict__ bo,
                       const float* __restrict__ ln_s, const float* __restrict__ ln_b) {
  int p = blockIdx.x * 4 + (threadIdx.x >> 6);
  int lane = threadIdx.x & 63;
  int cbase = p & ~(NPT - 1);     // first point of this cloud

  float px = pos[p * 3 + 0], py = pos[p * 3 + 1], pz = pos[p * 3 + 2];
  float wpe0 = Wpe[0 * HH + lane], wpe1 = Wpe[1 * HH + lane], wpe2 = Wpe[2 * HH + lane];
  float wpd0 = Wpd[0 * HH + lane], wpd1 = Wpd[1 * HH + lane], wpd2 = Wpd[2 * HH + lane];
  float bpeh = bpe[lane], bpdh = bpd[lane];

  float pe_i = bpeh + px * wpe0 + py * wpe1 + pz * wpe2;
  float qp = qb[p * HH + lane] + pe_i;
  float wa = Wa[lane];
  float ba0 = ba[0];

  const int* ni = nidx + p * KNN_K;
  float vj[KNN_K], logit[KNN_K];

#pragma unroll
  for (int jj = 0; jj < KNN_K; ++jj) {
    int g = cbase + ni[jj];
    float kv = kb[g * HH + lane];
    vj[jj] = vb[g * HH + lane];
    float jx = pos[g * 3 + 0], jy = pos[g * 3 + 1], jz = pos[g * 3 + 2];
    float pe_j = bpeh + jx * wpe0 + jy * wpe1 + jz * wpe2;
    float pd = bpdh + (jx - px) * wpd0 + (jy - py) * wpd1 + (jz - pz) * wpd2;
    float t = qp * (kv + pe_j + pd) * 0.125f * wa;
    logit[jj] = wave_sum64(t) + ba0;
  }

  // softmax over 16 (replicated across lanes)
  float m = logit[0];
#pragma unroll
  for (int jj = 1; jj < KNN_K; ++jj) m = fmaxf(m, logit[jj]);
  float s = 0.f;
#pragma unroll
  for (int jj = 0; jj < KNN_K; ++jj) { logit[jj] = expf(logit[jj] - m); s += logit[jj]; }
  float out = 0.f;
#pragma unroll
  for (int jj = 0; jj < KNN_K; ++jj) out += (logit[jj] / s) * vj[jj];

  // y = gelu(out @ Wo + bo)
  float y = bo[lane];
#pragma unroll 8
  for (int g = 0; g < HH; ++g) {
    float og = __shfl(out, g, 64);
    y += og * Wo[g * HH + lane];
  }
  y = gelu_f(y);

  // residual + layernorm
  float xn = x[p * HH + lane] + y;
  float mu = wave_sum64(xn) * (1.0f / HH);
  float d = xn - mu;
  float var = wave_sum64(d * d) * (1.0f / HH);
  float r = rsqrtf(var + 1e-6f);
  x[p * HH + lane] = d * r * ln_s[lane] + ln_b[lane];
}

// ---------------- K4: max over N -------------------------------------------
__global__ void k_pool(const float* __restrict__ x, float* __restrict__ pooled) {
  __shared__ float red[4][HH];
  int bs = blockIdx.x;
  int h = threadIdx.x & 63;
  int c = threadIdx.x >> 6;
  const float* xp = x + bs * NPT * HH;
  float m = -FLT_MAX;
  for (int n = c; n < NPT; n += 4) m = fmaxf(m, xp[n * HH + h]);
  red[c][h] = m;
  __syncthreads();
  if (c == 0) {
    m = fmaxf(fmaxf(red[0][h], red[1][h]), fmaxf(red[2][h], red[3][h]));
    pooled[bs * HH + h] = m;
  }
}

// ---------------- K5: set-encoder layer + final LN + max over S -------------
__global__ __launch_bounds__(512) void k_enc(
    const float* __restrict__ pooled,
    const float* __restrict__ Wek, const float* __restrict__ bek,
    const float* __restrict__ Weq, const float* __restrict__ beq,
    const float* __restrict__ Wev, const float* __restrict__ bev,
    const float* __restrict__ We1, const float* __restrict__ be1,
    const float* __restrict__ We2, const float* __restrict__ be2,
    const float* __restrict__ ln2_s, const float* __restrict__ ln2_b,
    float* __restrict__ out) {
  __shared__ float xs[8][HH], ks[8][HH], vs[8][HH], x2[8][HH];
  int b = blockIdx.x;
  int t = threadIdx.x >> 6;     // token 0..7
  int h = threadIdx.x & 63;
  const float* xp = pooled + b * 8 * HH;
  xs[t][h] = xp[t * HH + h];
  __syncthreads();

  float kk = bek[h], qq = beq[h], vv = bev[h];
#pragma unroll 8
  for (int g = 0; g < HH; ++g) {
    float xv = xs[t][g];
    kk += xv * Wek[g * HH + h];
    qq += xv * Weq[g * HH + h];
    vv += xv * Wev[g * HH + h];
  }
  ks[t][h] = kk;
  vs[t][h] = vv;
  __syncthreads();

  float logit[8];
#pragma unroll
  for (int s = 0; s < 8; ++s) {
    float tt = qq * ks[s][h];
    logit[s] = wave_sum64(tt) * 0.125f;
  }
  float m = logit[0];
#pragma unroll
  for (int s = 1; s < 8; ++s) m = fmaxf(m, logit[s]);
  float ssum = 0.f;
#pragma unroll
  for (int s = 0; s < 8; ++s) { logit[s] = expf(logit[s] - m); ssum += logit[s]; }
  float o = 0.f;
#pragma unroll
  for (int s = 0; s < 8; ++s) o += (logit[s] / ssum) * vs[s][h];

  float h1 = be1[h];
#pragma unroll 8
  for (int g = 0; g < HH; ++g) h1 += __shfl(o, g, 64) * We1[g * HH + h];
  h1 = gelu_f(h1);
  float h2 = be2[h];
#pragma unroll 8
  for (int g = 0; g < HH; ++g) h2 += __shfl(h1, g, 64) * We2[g * HH + h];

  float xn = xs[t][h] + h2;
  float mu = wave_sum64(xn) * (1.0f / HH);
  float d = xn - mu;
  float var = wave_sum64(d * d) * (1.0f / HH);
  float yv = d * rsqrtf(var + 1e-6f) * ln2_s[h] + ln2_b[h];
  x2[t][h] = yv;
  __syncthreads();
  if (t == 0) {
    float mm = x2[0][h];
#pragma unroll
    for (int s = 1; s < 8; ++s) mm = fmaxf(mm, x2[s][h]);
    out[b * HH + h] = mm;
  }
}

// ---------------------------------------------------------------------------
extern "C" void kernel_launch(void* const* d_in, const int* in_sizes, int n_in,
                              void* d_out, int out_size, void* d_ws, size_t ws_size,
                              hipStream_t stream) {
  const float* points = (const float*)d_in[0];
  const float* w_in   = (const float*)d_in[1];
  const float* b_in   = (const float*)d_in[2];
  const float* Wq     = (const float*)d_in[3];
  const float* bq     = (const float*)d_in[4];
  const float* Wk     = (const float*)d_in[5];
  const float* bk     = (const float*)d_in[6];
  const float* Wv     = (const float*)d_in[7];
  const float* bv     = (const float*)d_in[8];
  const float* Wpe    = (const float*)d_in[9];
  const float* bpe    = (const float*)d_in[10];
  const float* Wpd    = (const float*)d_in[11];
  const float* bpd    = (const float*)d_in[12];
  const float* Wa     = (const float*)d_in[13];
  const float* ba     = (const float*)d_in[14];
  const float* Wo     = (const float*)d_in[15];
  const float* bo     = (const float*)d_in[16];
  const float* ln_s   = (const float*)d_in[17];
  const float* ln_b   = (const float*)d_in[18];
  const float* Wek    = (const float*)d_in[19];
  const float* bek    = (const float*)d_in[20];
  const float* Weq    = (const float*)d_in[21];
  const float* beq    = (const float*)d_in[22];
  const float* Wev    = (const float*)d_in[23];
  const float* bev    = (const float*)d_in[24];
  const float* We1    = (const float*)d_in[25];
  const float* be1    = (const float*)d_in[26];
  const float* We2    = (const float*)d_in[27];
  const float* be2    = (const float*)d_in[28];
  const float* ln2_s  = (const float*)d_in[29];
  const float* ln2_b  = (const float*)d_in[30];

  float* ws     = (float*)d_ws;
  float* pos    = ws;                     // 3*PTOT
  float* xbuf   = pos  + 3 * PTOT;        // 64*PTOT
  float* qbuf   = xbuf + 64 * PTOT;
  float* kbuf   = qbuf + 64 * PTOT;
  float* vbuf   = kbuf + 64 * PTOT;
  float* pooled = vbuf + 64 * PTOT;       // 32*64
  int*   nidx   = (int*)(pooled + NCL * HH);  // 16*PTOT ints

  k_inproj<<<PTOT / 4, 256, 0, stream>>>(points, w_in, b_in, xbuf, pos);
  k_knn<<<NCL * 256, 256, 0, stream>>>(pos, nidx);

  for (int l = 0; l < 3; ++l) {
    k_qkv<<<PTOT / 4, 256, 0, stream>>>(xbuf,
        Wq + l * HH * HH, bq + l * HH,
        Wk + l * HH * HH, bk + l * HH,
        Wv + l * HH * HH, bv + l * HH,
        qbuf, kbuf, vbuf);
    k_attn<<<PTOT / 4, 256, 0, stream>>>(xbuf, pos, nidx, qbuf, kbuf, vbuf,
        Wpe + l * 3 * HH, bpe + l * HH,
        Wpd + l * 3 * HH, bpd + l * HH,
        Wa + l * HH, ba + l,
        Wo + l * HH * HH, bo + l * HH,
        ln_s + l * HH, ln_b + l * HH);
  }

  k_pool<<<NCL, 256, 0, stream>>>(xbuf, pooled);
  k_enc<<<4, 512, 0, stream>>>(pooled, Wek, bek, Weq, beq, Wev, bev,
                               We1, be1, We2, be2, ln2_s, ln2_b, (float*)d_out);
}

// Round 3
// 406.979 us; speedup vs baseline: 2.4493x; 1.4257x over previous
//
#include <hip/hip_runtime.h>
#include <cfloat>
#include <cmath>

#define NPT   1024          // points per cloud
#define NCL   32            // clouds (B*S)
#define PTOT  32768         // total points
#define HH    64
#define KNN_K 16

#define RFL(x) __builtin_amdgcn_readfirstlane(x)

__device__ __forceinline__ float wave_sum64(float t) {
#pragma unroll
  for (int o = 32; o > 0; o >>= 1) t += __shfl_xor(t, o, 64);
  return t;
}

__device__ __forceinline__ float gelu_f(float z) {
  float zc = 0.7978845608028654f * (z + 0.044715f * z * z * z);
  float t = __expf(2.0f * zc);
  float th = 1.0f - 2.0f / (t + 1.0f);
  return 0.5f * z * (1.0f + th);
}

// ---------------- K0: input projection + pos4 extract -----------------------
__global__ void k_inproj(const float* __restrict__ pts,
                         const float* __restrict__ w_in,
                         const float* __restrict__ b_in,
                         float* __restrict__ x, float* __restrict__ pos4) {
  int p = blockIdx.x * 4 + (threadIdx.x >> 6);
  int h = threadIdx.x & 63;
  const float* pp = pts + p * 6;
  float acc = b_in[h];
#pragma unroll
  for (int f = 0; f < 6; ++f) acc += pp[f] * w_in[f * HH + h];
  x[p * HH + h] = acc;
  if (h < 4) pos4[p * 4 + h] = (h < 3) ? pp[h] : 0.0f;
}

// ---------------- K1: 16-NN, one wave per query point ----------------------
__global__ __launch_bounds__(256) void k_knn(const float* __restrict__ pos4,
                                             int* __restrict__ nidx) {
  __shared__ float sx[NPT], sy[NPT], sz[NPT];
  int cloud = blockIdx.x >> 8;            // 256 blocks per cloud
  int qbase = (blockIdx.x & 255) * 4;     // 4 queries (waves) per block
  const float4* cp4 = reinterpret_cast<const float4*>(pos4) + cloud * NPT;
  for (int j = threadIdx.x; j < NPT; j += 256) {
    float4 v = cp4[j];
    sx[j] = v.x; sy[j] = v.y; sz[j] = v.z;
  }
  __syncthreads();

  int wv = threadIdx.x >> 6;
  int lane = threadIdx.x & 63;
  int i = qbase + wv;                     // query index within cloud
  float qx = sx[i], qy = sy[i], qz = sz[i];

  float d[16];
#pragma unroll
  for (int c = 0; c < 16; ++c) {
    int j = c * 64 + lane;
    float dx = qx - sx[j], dy = qy - sy[j], dz = qz - sz[j];
    // exact IEEE, reference order: (dx*dx + dy*dy) + dz*dz, no fma contraction
    d[c] = __fadd_rn(__fadd_rn(__fmul_rn(dx, dx), __fmul_rn(dy, dy)),
                     __fmul_rn(dz, dz));
  }

  int obase = (cloud * NPT + i) * KNN_K;
  for (int r = 0; r < KNN_K; ++r) {
    float bd = d[0];
    int bc = 0;
#pragma unroll
    for (int c = 1; c < 16; ++c) {
      if (d[c] < bd) { bd = d[c]; bc = c; }
    }
    float gd = bd;
#pragma unroll
    for (int o = 32; o > 0; o >>= 1) gd = fminf(gd, __shfl_xor(gd, o, 64));
    int myidx = bc * 64 + lane;
    int cand = (bd == gd) ? myidx : 0x7fffffff;
    int gidx = cand;
#pragma unroll
    for (int o = 32; o > 0; o >>= 1) gidx = min(gidx, __shfl_xor(gidx, o, 64));
    if (lane == 0) nidx[obase + r] = gidx;
    int sel = (myidx == gidx) ? bc : 99;
#pragma unroll
    for (int c = 0; c < 16; ++c) {
      d[c] = (c == sel) ? FLT_MAX : d[c];
    }
  }
}

// ---------------- K2: register-tiled qkv GEMM with pe/pd folding ------------
// qq = x@Wq + bq + (bpe + pos.Wpe)                      [q + pe_i]
// kk = x@Wk + bk + (bpe + pos.Wpe) + (bpd + pos.Wpd)    [k + pe_j + pd_j]
// v  = x@Wv + bv;  kkv stores (kk,v) interleaved float2 per point-row.
__global__ __launch_bounds__(256) void k_qkv_gemm(
    const float* __restrict__ x, const float* __restrict__ pos4,
    const float* __restrict__ Wq, const float* __restrict__ bq,
    const float* __restrict__ Wk, const float* __restrict__ bk,
    const float* __restrict__ Wv, const float* __restrict__ bv,
    const float* __restrict__ Wpe, const float* __restrict__ bpe,
    const float* __restrict__ Wpd, const float* __restrict__ bpd,
    float* __restrict__ qq, float* __restrict__ kkv) {
  int lane = threadIdx.x & 63;
  int pb = RFL(blockIdx.x * 32 + (threadIdx.x >> 6) * 8);
  const float* xw = x + (size_t)pb * HH;
  const float4* posw = reinterpret_cast<const float4*>(pos4) + pb;

  float wpe0 = Wpe[lane], wpe1 = Wpe[HH + lane], wpe2 = Wpe[2 * HH + lane];
  float wpd0 = Wpd[lane], wpd1 = Wpd[HH + lane], wpd2 = Wpd[2 * HH + lane];
  float we0 = wpe0 + wpd0, we1 = wpe1 + wpd1, we2 = wpe2 + wpd2;
  float bqq = bq[lane] + bpe[lane];
  float bkk = bk[lane] + bpe[lane] + bpd[lane];
  float bvv = bv[lane];

  float aq[8], ak[8], av[8];
#pragma unroll
  for (int p = 0; p < 8; ++p) { aq[p] = bqq; ak[p] = bkk; av[p] = bvv; }

#pragma unroll
  for (int c = 0; c < 8; ++c) {
    float wq8[8], wk8[8], wv8[8];
#pragma unroll
    for (int j = 0; j < 8; ++j) {
      int g = c * 8 + j;
      wq8[j] = Wq[g * HH + lane];
      wk8[j] = Wk[g * HH + lane];
      wv8[j] = Wv[g * HH + lane];
    }
#pragma unroll
    for (int p = 0; p < 8; ++p) {
#pragma unroll
      for (int j = 0; j < 8; ++j) {
        float xv = xw[p * HH + c * 8 + j];   // wave-uniform -> scalar load
        aq[p] = fmaf(xv, wq8[j], aq[p]);
        ak[p] = fmaf(xv, wk8[j], ak[p]);
        av[p] = fmaf(xv, wv8[j], av[p]);
      }
    }
  }

#pragma unroll
  for (int p = 0; p < 8; ++p) {
    float4 pp = posw[p];
    float qv = aq[p] + pp.x * wpe0 + pp.y * wpe1 + pp.z * wpe2;
    float kv = ak[p] + pp.x * we0 + pp.y * we1 + pp.z * we2;
    qq[(size_t)(pb + p) * HH + lane] = qv;
    reinterpret_cast<float2*>(kkv + ((size_t)(pb + p) << 7))[lane] =
        make_float2(kv, av[p]);
  }
}

// ---------------- K3: attention core (logits + softmax + PV) ----------------
// logit_j = sum_h u_h*(kk_jh) - C0,  u = qq*wa/8,  C0 = sum_h u_h*(pos_i.Wpd)_h - ba
// Writes out (pre-Wo attention output) in place over qq.
__global__ __launch_bounds__(256) void k_attn_core(
    float* __restrict__ qq, const float* __restrict__ kkv,
    const int* __restrict__ nidx, const float* __restrict__ pos4,
    const float* __restrict__ Wpd, const float* __restrict__ Wa,
    const float* __restrict__ ba) {
  int lane = threadIdx.x & 63;
  int pu = RFL(blockIdx.x * 4 + (threadIdx.x >> 6));
  int cbase = pu & ~(NPT - 1);

  float4 pp = reinterpret_cast<const float4*>(pos4)[pu];
  float u = qq[(size_t)pu * HH + lane] * Wa[lane] * 0.125f;
  float pdq = pp.x * Wpd[lane] + pp.y * Wpd[HH + lane] + pp.z * Wpd[2 * HH + lane];
  float C0 = wave_sum64(u * pdq) - ba[0];

  const int* niw = nidx + (size_t)pu * KNN_K;
  int nj[KNN_K];
#pragma unroll
  for (int jj = 0; jj < KNN_K; ++jj) nj[jj] = niw[jj];

  float vj[KNN_K], lg[KNN_K];
#pragma unroll
  for (int jj = 0; jj < KNN_K; ++jj) {
    float2 kv = reinterpret_cast<const float2*>(
        kkv + ((size_t)(cbase + nj[jj]) << 7))[lane];
    vj[jj] = kv.y;
    lg[jj] = wave_sum64(u * kv.x) - C0;
  }

  float m = lg[0];
#pragma unroll
  for (int jj = 1; jj < KNN_K; ++jj) m = fmaxf(m, lg[jj]);
  float s = 0.f, oacc = 0.f;
#pragma unroll
  for (int jj = 0; jj < KNN_K; ++jj) {
    float e = __expf(lg[jj] - m);
    s += e;
    oacc = fmaf(e, vj[jj], oacc);
  }
  qq[(size_t)pu * HH + lane] = oacc / s;
}

// ---------------- K4: Wo GEMM + gelu + residual + LN ------------------------
__global__ __launch_bounds__(256) void k_wo_ln(
    const float* __restrict__ outb, const float* __restrict__ Wo,
    const float* __restrict__ bo, float* __restrict__ x,
    const float* __restrict__ ln_s, const float* __restrict__ ln_b) {
  int lane = threadIdx.x & 63;
  int pb = RFL(blockIdx.x * 32 + (threadIdx.x >> 6) * 8);
  const float* ow = outb + (size_t)pb * HH;

  float acc[8];
  float b0 = bo[lane];
#pragma unroll
  for (int p = 0; p < 8; ++p) acc[p] = b0;

#pragma unroll
  for (int c = 0; c < 8; ++c) {
    float w8[8];
#pragma unroll
    for (int j = 0; j < 8; ++j) w8[j] = Wo[(c * 8 + j) * HH + lane];
#pragma unroll
    for (int p = 0; p < 8; ++p) {
#pragma unroll
      for (int j = 0; j < 8; ++j) {
        float ov = ow[p * HH + c * 8 + j];   // wave-uniform -> scalar load
        acc[p] = fmaf(ov, w8[j], acc[p]);
      }
    }
  }

  float sg = ln_s[lane], bg = ln_b[lane];
#pragma unroll
  for (int p = 0; p < 8; ++p) {
    float y = gelu_f(acc[p]);
    float xn = x[(size_t)(pb + p) * HH + lane] + y;
    float mu = wave_sum64(xn) * (1.0f / HH);
    float dd = xn - mu;
    float var = wave_sum64(dd * dd) * (1.0f / HH);
    x[(size_t)(pb + p) * HH + lane] = dd * rsqrtf(var + 1e-6f) * sg + bg;
  }
}

// ---------------- K5: max over N -------------------------------------------
__global__ void k_pool(const float* __restrict__ x, float* __restrict__ pooled) {
  __shared__ float red[4][HH];
  int bs = blockIdx.x;
  int h = threadIdx.x & 63;
  int c = threadIdx.x >> 6;
  const float* xp = x + bs * NPT * HH;
  float m = -FLT_MAX;
  for (int n = c; n < NPT; n += 4) m = fmaxf(m, xp[n * HH + h]);
  red[c][h] = m;
  __syncthreads();
  if (c == 0) {
    m = fmaxf(fmaxf(red[0][h], red[1][h]), fmaxf(red[2][h], red[3][h]));
    pooled[bs * HH + h] = m;
  }
}

// ---------------- K6: set-encoder layer + final LN + max over S -------------
__global__ __launch_bounds__(512) void k_enc(
    const float* __restrict__ pooled,
    const float* __restrict__ Wek, const float* __restrict__ bek,
    const float* __restrict__ Weq, const float* __restrict__ beq,
    const float* __restrict__ Wev, const float* __restrict__ bev,
    const float* __restrict__ We1, const float* __restrict__ be1,
    const float* __restrict__ We2, const float* __restrict__ be2,
    const float* __restrict__ ln2_s, const float* __restrict__ ln2_b,
    float* __restrict__ out) {
  __shared__ float xs[8][HH], ks[8][HH], vs[8][HH], x2[8][HH];
  int b = blockIdx.x;
  int t = threadIdx.x >> 6;     // token 0..7
  int h = threadIdx.x & 63;
  const float* xp = pooled + b * 8 * HH;
  xs[t][h] = xp[t * HH + h];
  __syncthreads();

  float kk = bek[h], qq = beq[h], vv = bev[h];
#pragma unroll 8
  for (int g = 0; g < HH; ++g) {
    float xv = xs[t][g];
    kk += xv * Wek[g * HH + h];
    qq += xv * Weq[g * HH + h];
    vv += xv * Wev[g * HH + h];
  }
  ks[t][h] = kk;
  vs[t][h] = vv;
  __syncthreads();

  float logit[8];
#pragma unroll
  for (int s = 0; s < 8; ++s) {
    float tt = qq * ks[s][h];
    logit[s] = wave_sum64(tt) * 0.125f;
  }
  float m = logit[0];
#pragma unroll
  for (int s = 1; s < 8; ++s) m = fmaxf(m, logit[s]);
  float ssum = 0.f;
#pragma unroll
  for (int s = 0; s < 8; ++s) { logit[s] = expf(logit[s] - m); ssum += logit[s]; }
  float o = 0.f;
#pragma unroll
  for (int s = 0; s < 8; ++s) o += (logit[s] / ssum) * vs[s][h];

  float h1 = be1[h];
#pragma unroll 8
  for (int g = 0; g < HH; ++g) h1 += __shfl(o, g, 64) * We1[g * HH + h];
  h1 = gelu_f(h1);
  float h2 = be2[h];
#pragma unroll 8
  for (int g = 0; g < HH; ++g) h2 += __shfl(h1, g, 64) * We2[g * HH + h];

  float xn = xs[t][h] + h2;
  float mu = wave_sum64(xn) * (1.0f / HH);
  float d = xn - mu;
  float var = wave_sum64(d * d) * (1.0f / HH);
  float yv = d * rsqrtf(var + 1e-6f) * ln2_s[h] + ln2_b[h];
  x2[t][h] = yv;
  __syncthreads();
  if (t == 0) {
    float mm = x2[0][h];
#pragma unroll
    for (int s = 1; s < 8; ++s) mm = fmaxf(mm, x2[s][h]);
    out[b * HH + h] = mm;
  }
}

// ---------------------------------------------------------------------------
extern "C" void kernel_launch(void* const* d_in, const int* in_sizes, int n_in,
                              void* d_out, int out_size, void* d_ws, size_t ws_size,
                              hipStream_t stream) {
  const float* points = (const float*)d_in[0];
  const float* w_in   = (const float*)d_in[1];
  const float* b_in   = (const float*)d_in[2];
  const float* Wq     = (const float*)d_in[3];
  const float* bq     = (const float*)d_in[4];
  const float* Wk     = (const float*)d_in[5];
  const float* bk     = (const float*)d_in[6];
  const float* Wv     = (const float*)d_in[7];
  const float* bv     = (const float*)d_in[8];
  const float* Wpe    = (const float*)d_in[9];
  const float* bpe    = (const float*)d_in[10];
  const float* Wpd    = (const float*)d_in[11];
  const float* bpd    = (const float*)d_in[12];
  const float* Wa     = (const float*)d_in[13];
  const float* ba     = (const float*)d_in[14];
  const float* Wo     = (const float*)d_in[15];
  const float* bo     = (const float*)d_in[16];
  const float* ln_s   = (const float*)d_in[17];
  const float* ln_b   = (const float*)d_in[18];
  const float* Wek    = (const float*)d_in[19];
  const float* bek    = (const float*)d_in[20];
  const float* Weq    = (const float*)d_in[21];
  const float* beq    = (const float*)d_in[22];
  const float* Wev    = (const float*)d_in[23];
  const float* bev    = (const float*)d_in[24];
  const float* We1    = (const float*)d_in[25];
  const float* be1    = (const float*)d_in[26];
  const float* We2    = (const float*)d_in[27];
  const float* be2    = (const float*)d_in[28];
  const float* ln2_s  = (const float*)d_in[29];
  const float* ln2_b  = (const float*)d_in[30];

  float* ws     = (float*)d_ws;
  float* pos4   = ws;                      // 4*PTOT
  float* xbuf   = pos4 + 4 * PTOT;         // 64*PTOT
  float* qbuf   = xbuf + 64 * PTOT;        // 64*PTOT (qq, then attn-out)
  float* kkv    = qbuf + 64 * PTOT;        // 128*PTOT (kk,v interleaved)
  float* pooled = kkv + 128 * PTOT;        // NCL*HH
  int*   nidx   = (int*)(pooled + NCL * HH);  // 16*PTOT ints

  k_inproj<<<PTOT / 4, 256, 0, stream>>>(points, w_in, b_in, xbuf, pos4);
  k_knn<<<NCL * 256, 256, 0, stream>>>(pos4, nidx);

  for (int l = 0; l < 3; ++l) {
    k_qkv_gemm<<<PTOT / 32, 256, 0, stream>>>(xbuf, pos4,
        Wq + l * HH * HH, bq + l * HH,
        Wk + l * HH * HH, bk + l * HH,
        Wv + l * HH * HH, bv + l * HH,
        Wpe + l * 3 * HH, bpe + l * HH,
        Wpd + l * 3 * HH, bpd + l * HH,
        qbuf, kkv);
    k_attn_core<<<PTOT / 4, 256, 0, stream>>>(qbuf, kkv, nidx, pos4,
        Wpd + l * 3 * HH, Wa + l * HH, ba + l);
    k_wo_ln<<<PTOT / 32, 256, 0, stream>>>(qbuf,
        Wo + l * HH * HH, bo + l * HH, xbuf,
        ln_s + l * HH, ln_b + l * HH);
  }

  k_pool<<<NCL, 256, 0, stream>>>(xbuf, pooled);
  k_enc<<<4, 512, 0, stream>>>(pooled, Wek, bek, Weq, beq, Wev, bev,
                               We1, be1, We2, be2, ln2_s, ln2_b, (float*)d_out);
}

// Round 4
// 360.890 us; speedup vs baseline: 2.7621x; 1.1277x over previous
//
#include <hip/hip_runtime.h>
#include <cfloat>
#include <cmath>
#include <cstdint>

#define NPT   1024          // points per cloud
#define NCL   32            // clouds (B*S)
#define PTOT  32768         // total points
#define HH    64
#define KNN_K 16

#define RFL(x) __builtin_amdgcn_readfirstlane(x)

__device__ __forceinline__ float wave_sum64(float t) {
#pragma unroll
  for (int o = 32; o > 0; o >>= 1) t += __shfl_xor(t, o, 64);
  return t;
}

__device__ __forceinline__ double dshfl_xor(double v, int m) {
  union { double d; int i[2]; } u;
  u.d = v;
  u.i[0] = __shfl_xor(u.i[0], m, 64);
  u.i[1] = __shfl_xor(u.i[1], m, 64);
  return u.d;
}

__device__ __forceinline__ float gelu_f(float z) {
  float zc = 0.7978845608028654f * (z + 0.044715f * z * z * z);
  float t = __expf(2.0f * zc);
  float th = 1.0f - 2.0f / (t + 1.0f);
  return 0.5f * z * (1.0f + th);
}

// ---------------- K0: input projection + pos4 extract -----------------------
__global__ void k_inproj(const float* __restrict__ pts,
                         const float* __restrict__ w_in,
                         const float* __restrict__ b_in,
                         float* __restrict__ x, float* __restrict__ pos4) {
  int p = blockIdx.x * 4 + (threadIdx.x >> 6);
  int h = threadIdx.x & 63;
  const float* pp = pts + p * 6;
  float acc = b_in[h];
#pragma unroll
  for (int f = 0; f < 6; ++f) acc += pp[f] * w_in[f * HH + h];
  x[p * HH + h] = acc;
  if (h < 4) pos4[p * 4 + h] = (h < 3) ? pp[h] : 0.0f;
}

// ---------------- K1: 16-NN via bitonic top-k on f64-packed keys ------------
// key = (1<<62) | (float_bits(d2) << 20) | global_idx  — positive normal f64,
// so v_min_f64/v_max_f64 give exact (distance, index)-lexicographic order ==
// jax.lax.top_k semantics. Unique keys -> no stability issues.
__global__ __launch_bounds__(256) void k_knn(const float* __restrict__ pos4,
                                             int* __restrict__ nidx) {
  __shared__ float sx[NPT], sy[NPT], sz[NPT];
  int cloud = blockIdx.x >> 8;            // 256 blocks per cloud
  int qbase = (blockIdx.x & 255) * 4;     // 4 queries (waves) per block
  const float4* cp4 = reinterpret_cast<const float4*>(pos4) + cloud * NPT;
  for (int j = threadIdx.x; j < NPT; j += 256) {
    float4 v = cp4[j];
    sx[j] = v.x; sy[j] = v.y; sz[j] = v.z;
  }
  __syncthreads();

  int wv = threadIdx.x >> 6;
  int lane = threadIdx.x & 63;
  int i = qbase + wv;                     // query index within cloud
  float qx = sx[i], qy = sy[i], qz = sz[i];

  double m[16];
#pragma unroll
  for (int c = 0; c < 16; ++c) {
    int j = c * 64 + lane;
    float dx = qx - sx[j], dy = qy - sy[j], dz = qz - sz[j];
    // exact IEEE, reference order: (dx*dx + dy*dy) + dz*dz, no fma contraction
    float d2 = __fadd_rn(__fadd_rn(__fmul_rn(dx, dx), __fmul_rn(dy, dy)),
                         __fmul_rn(dz, dz));
    uint64_t key = (1ULL << 62) | ((uint64_t)__float_as_uint(d2) << 20)
                 | (uint64_t)j;
    m[c] = __longlong_as_double((long long)key);
  }

  // per-lane bitonic sort of 16, ascending
#pragma unroll
  for (int k = 2; k <= 16; k <<= 1) {
#pragma unroll
    for (int j = k >> 1; j > 0; j >>= 1) {
#pragma unroll
      for (int a = 0; a < 16; ++a) {
        int b = a ^ j;
        if (b > a) {
          double lo = fmin(m[a], m[b]);
          double hi = fmax(m[a], m[b]);
          bool up = (a & k) == 0;
          m[a] = up ? lo : hi;
          m[b] = up ? hi : lo;
        }
      }
    }
  }

  // 6 cross-lane butterfly merge levels: keep min-16 of (mine, partner's)
#pragma unroll
  for (int w = 1; w <= 32; w <<= 1) {
    double t[16];
#pragma unroll
    for (int a = 0; a < 16; ++a) t[a] = dshfl_xor(m[15 - a], w);
#pragma unroll
    for (int a = 0; a < 16; ++a) m[a] = fmin(m[a], t[a]);
    // m is bitonic; 4-stage bitonic merge -> ascending
#pragma unroll
    for (int j = 8; j > 0; j >>= 1) {
#pragma unroll
      for (int a = 0; a < 16; ++a) {
        int b = a ^ j;
        if (b > a) {
          double lo = fmin(m[a], m[b]);
          m[b] = fmax(m[a], m[b]);
          m[a] = lo;
        }
      }
    }
  }

  // all lanes hold identical sorted top-16; lane 0 writes indices
  if (lane == 0) {
    int obase = (cloud * NPT + i) * KNN_K;
    int4* o = reinterpret_cast<int4*>(nidx + obase);
#pragma unroll
    for (int g = 0; g < 4; ++g) {
      int4 r;
      r.x = (int)(__double_as_longlong(m[g * 4 + 0]) & 1023);
      r.y = (int)(__double_as_longlong(m[g * 4 + 1]) & 1023);
      r.z = (int)(__double_as_longlong(m[g * 4 + 2]) & 1023);
      r.w = (int)(__double_as_longlong(m[g * 4 + 3]) & 1023);
      o[g] = r;
    }
  }
}

// ---------------- K2: register-tiled qkv GEMM with pe/pd folding ------------
__global__ __launch_bounds__(256) void k_qkv_gemm(
    const float* __restrict__ x, const float* __restrict__ pos4,
    const float* __restrict__ Wq, const float* __restrict__ bq,
    const float* __restrict__ Wk, const float* __restrict__ bk,
    const float* __restrict__ Wv, const float* __restrict__ bv,
    const float* __restrict__ Wpe, const float* __restrict__ bpe,
    const float* __restrict__ Wpd, const float* __restrict__ bpd,
    float* __restrict__ qq, float* __restrict__ kkv) {
  int lane = threadIdx.x & 63;
  int pb = RFL(blockIdx.x * 32 + (threadIdx.x >> 6) * 8);
  const float* xw = x + (size_t)pb * HH;
  const float4* posw = reinterpret_cast<const float4*>(pos4) + pb;

  float wpe0 = Wpe[lane], wpe1 = Wpe[HH + lane], wpe2 = Wpe[2 * HH + lane];
  float wpd0 = Wpd[lane], wpd1 = Wpd[HH + lane], wpd2 = Wpd[2 * HH + lane];
  float we0 = wpe0 + wpd0, we1 = wpe1 + wpd1, we2 = wpe2 + wpd2;
  float bqq = bq[lane] + bpe[lane];
  float bkk = bk[lane] + bpe[lane] + bpd[lane];
  float bvv = bv[lane];

  float aq[8], ak[8], av[8];
#pragma unroll
  for (int p = 0; p < 8; ++p) { aq[p] = bqq; ak[p] = bkk; av[p] = bvv; }

#pragma unroll
  for (int c = 0; c < 8; ++c) {
    float wq8[8], wk8[8], wv8[8];
#pragma unroll
    for (int j = 0; j < 8; ++j) {
      int g = c * 8 + j;
      wq8[j] = Wq[g * HH + lane];
      wk8[j] = Wk[g * HH + lane];
      wv8[j] = Wv[g * HH + lane];
    }
#pragma unroll
    for (int p = 0; p < 8; ++p) {
#pragma unroll
      for (int j = 0; j < 8; ++j) {
        float xv = xw[p * HH + c * 8 + j];   // wave-uniform -> scalar load
        aq[p] = fmaf(xv, wq8[j], aq[p]);
        ak[p] = fmaf(xv, wk8[j], ak[p]);
        av[p] = fmaf(xv, wv8[j], av[p]);
      }
    }
  }

#pragma unroll
  for (int p = 0; p < 8; ++p) {
    float4 pp = posw[p];
    float qv = aq[p] + pp.x * wpe0 + pp.y * wpe1 + pp.z * wpe2;
    float kv = ak[p] + pp.x * we0 + pp.y * we1 + pp.z * we2;
    qq[(size_t)(pb + p) * HH + lane] = qv;
    reinterpret_cast<float2*>(kkv + ((size_t)(pb + p) << 7))[lane] =
        make_float2(kv, av[p]);
  }
}

// ---------------- K3: attention core (logits + softmax + PV) ----------------
// XCD-chunked swizzle: each XCD owns 4 contiguous clouds -> kkv slice (2 MB)
// stays resident in that XCD's L2.
__global__ __launch_bounds__(256) void k_attn_core(
    float* __restrict__ qq, const float* __restrict__ kkv,
    const int* __restrict__ nidx, const float* __restrict__ pos4,
    const float* __restrict__ Wpd, const float* __restrict__ Wa,
    const float* __restrict__ ba) {
  int lane = threadIdx.x & 63;
  int bid = blockIdx.x;
  int vb = (bid & 7) * (PTOT / 4 / 8) + (bid >> 3);   // XCD-chunked remap
  int pu = RFL(vb * 4 + (threadIdx.x >> 6));
  int cbase = pu & ~(NPT - 1);

  float4 pp = reinterpret_cast<const float4*>(pos4)[pu];
  float u = qq[(size_t)pu * HH + lane] * Wa[lane] * 0.125f;
  float pdq = pp.x * Wpd[lane] + pp.y * Wpd[HH + lane] + pp.z * Wpd[2 * HH + lane];
  float C0 = wave_sum64(u * pdq) - ba[0];

  const int4* niw = reinterpret_cast<const int4*>(nidx + (size_t)pu * KNN_K);
  int nj[KNN_K];
#pragma unroll
  for (int g = 0; g < 4; ++g) {
    int4 r = niw[g];
    nj[g * 4 + 0] = r.x; nj[g * 4 + 1] = r.y;
    nj[g * 4 + 2] = r.z; nj[g * 4 + 3] = r.w;
  }

  float vj[KNN_K], lg[KNN_K];
#pragma unroll
  for (int jj = 0; jj < KNN_K; ++jj) {
    float2 kv = reinterpret_cast<const float2*>(
        kkv + ((size_t)(cbase + nj[jj]) << 7))[lane];
    vj[jj] = kv.y;
    lg[jj] = wave_sum64(u * kv.x) - C0;
  }

  float m = lg[0];
#pragma unroll
  for (int jj = 1; jj < KNN_K; ++jj) m = fmaxf(m, lg[jj]);
  float s = 0.f, oacc = 0.f;
#pragma unroll
  for (int jj = 0; jj < KNN_K; ++jj) {
    float e = __expf(lg[jj] - m);
    s += e;
    oacc = fmaf(e, vj[jj], oacc);
  }
  qq[(size_t)pu * HH + lane] = oacc / s;
}

// ---------------- K4: Wo GEMM + gelu + residual + LN ------------------------
__global__ __launch_bounds__(256) void k_wo_ln(
    const float* __restrict__ outb, const float* __restrict__ Wo,
    const float* __restrict__ bo, float* __restrict__ x,
    const float* __restrict__ ln_s, const float* __restrict__ ln_b) {
  int lane = threadIdx.x & 63;
  int pb = RFL(blockIdx.x * 32 + (threadIdx.x >> 6) * 8);
  const float* ow = outb + (size_t)pb * HH;

  float acc[8];
  float b0 = bo[lane];
#pragma unroll
  for (int p = 0; p < 8; ++p) acc[p] = b0;

#pragma unroll
  for (int c = 0; c < 8; ++c) {
    float w8[8];
#pragma unroll
    for (int j = 0; j < 8; ++j) w8[j] = Wo[(c * 8 + j) * HH + lane];
#pragma unroll
    for (int p = 0; p < 8; ++p) {
#pragma unroll
      for (int j = 0; j < 8; ++j) {
        float ov = ow[p * HH + c * 8 + j];   // wave-uniform -> scalar load
        acc[p] = fmaf(ov, w8[j], acc[p]);
      }
    }
  }

  float sg = ln_s[lane], bg = ln_b[lane];
#pragma unroll
  for (int p = 0; p < 8; ++p) {
    float y = gelu_f(acc[p]);
    float xn = x[(size_t)(pb + p) * HH + lane] + y;
    float mu = wave_sum64(xn) * (1.0f / HH);
    float dd = xn - mu;
    float var = wave_sum64(dd * dd) * (1.0f / HH);
    x[(size_t)(pb + p) * HH + lane] = dd * rsqrtf(var + 1e-6f) * sg + bg;
  }
}

// ---------------- K5: partial max over N (stage 1: 128 rows/block) ----------
__global__ __launch_bounds__(256) void k_pool1(const float* __restrict__ x,
                                               float* __restrict__ partial) {
  __shared__ float red[4][HH];
  int cloud = blockIdx.x >> 3, chunk = blockIdx.x & 7;
  int lane = threadIdx.x & 63, wv = threadIdx.x >> 6;
  const float* xp = x + ((size_t)cloud * NPT + chunk * 128 + wv * 32) * HH;
  float mx = -FLT_MAX;
#pragma unroll 8
  for (int n = 0; n < 32; ++n) mx = fmaxf(mx, xp[n * HH + lane]);
  red[wv][lane] = mx;
  __syncthreads();
  if (wv == 0) {
    mx = fmaxf(fmaxf(red[0][lane], red[1][lane]),
               fmaxf(red[2][lane], red[3][lane]));
    partial[(size_t)blockIdx.x * HH + lane] = mx;
  }
}

// ---------------- K6: fused pool-finish + set-encoder + final LN + max ------
__global__ __launch_bounds__(512) void k_enc(
    const float* __restrict__ partial,
    const float* __restrict__ Wek, const float* __restrict__ bek,
    const float* __restrict__ Weq, const float* __restrict__ beq,
    const float* __restrict__ Wev, const float* __restrict__ bev,
    const float* __restrict__ We1, const float* __restrict__ be1,
    const float* __restrict__ We2, const float* __restrict__ be2,
    const float* __restrict__ ln2_s, const float* __restrict__ ln2_b,
    float* __restrict__ out) {
  __shared__ float xs[8][HH], ks[8][HH], vs[8][HH], x2[8][HH];
  int b = blockIdx.x;
  int t = threadIdx.x >> 6;     // token (cloud-in-batch) 0..7
  int h = threadIdx.x & 63;
  // finish the N-max from 8 partials
  {
    const float* pp = partial + ((size_t)(b * 8 + t) * 8) * HH + h;
    float mx = pp[0];
#pragma unroll
    for (int c8 = 1; c8 < 8; ++c8) mx = fmaxf(mx, pp[c8 * HH]);
    xs[t][h] = mx;
  }
  __syncthreads();

  float kk = bek[h], qq = beq[h], vv = bev[h];
#pragma unroll 8
  for (int g = 0; g < HH; ++g) {
    float xv = xs[t][g];
    kk += xv * Wek[g * HH + h];
    qq += xv * Weq[g * HH + h];
    vv += xv * Wev[g * HH + h];
  }
  ks[t][h] = kk;
  vs[t][h] = vv;
  __syncthreads();

  float logit[8];
#pragma unroll
  for (int s = 0; s < 8; ++s) {
    float tt = qq * ks[s][h];
    logit[s] = wave_sum64(tt) * 0.125f;
  }
  float m = logit[0];
#pragma unroll
  for (int s = 1; s < 8; ++s) m = fmaxf(m, logit[s]);
  float ssum = 0.f;
#pragma unroll
  for (int s = 0; s < 8; ++s) { logit[s] = expf(logit[s] - m); ssum += logit[s]; }
  float o = 0.f;
#pragma unroll
  for (int s = 0; s < 8; ++s) o += (logit[s] / ssum) * vs[s][h];

  float h1 = be1[h];
#pragma unroll 8
  for (int g = 0; g < HH; ++g) h1 += __shfl(o, g, 64) * We1[g * HH + h];
  h1 = gelu_f(h1);
  float h2 = be2[h];
#pragma unroll 8
  for (int g = 0; g < HH; ++g) h2 += __shfl(h1, g, 64) * We2[g * HH + h];

  float xn = xs[t][h] + h2;
  float mu = wave_sum64(xn) * (1.0f / HH);
  float d = xn - mu;
  float var = wave_sum64(d * d) * (1.0f / HH);
  float yv = d * rsqrtf(var + 1e-6f) * ln2_s[h] + ln2_b[h];
  x2[t][h] = yv;
  __syncthreads();
  if (t == 0) {
    float mm = x2[0][h];
#pragma unroll
    for (int s = 1; s < 8; ++s) mm = fmaxf(mm, x2[s][h]);
    out[b * HH + h] = mm;
  }
}

// ---------------------------------------------------------------------------
extern "C" void kernel_launch(void* const* d_in, const int* in_sizes, int n_in,
                              void* d_out, int out_size, void* d_ws, size_t ws_size,
                              hipStream_t stream) {
  const float* points = (const float*)d_in[0];
  const float* w_in   = (const float*)d_in[1];
  const float* b_in   = (const float*)d_in[2];
  const float* Wq     = (const float*)d_in[3];
  const float* bq     = (const float*)d_in[4];
  const float* Wk     = (const float*)d_in[5];
  const float* bk     = (const float*)d_in[6];
  const float* Wv     = (const float*)d_in[7];
  const float* bv     = (const float*)d_in[8];
  const float* Wpe    = (const float*)d_in[9];
  const float* bpe    = (const float*)d_in[10];
  const float* Wpd    = (const float*)d_in[11];
  const float* bpd    = (const float*)d_in[12];
  const float* Wa     = (const float*)d_in[13];
  const float* ba     = (const float*)d_in[14];
  const float* Wo     = (const float*)d_in[15];
  const float* bo     = (const float*)d_in[16];
  const float* ln_s   = (const float*)d_in[17];
  const float* ln_b   = (const float*)d_in[18];
  const float* Wek    = (const float*)d_in[19];
  const float* bek    = (const float*)d_in[20];
  const float* Weq    = (const float*)d_in[21];
  const float* beq    = (const float*)d_in[22];
  const float* Wev    = (const float*)d_in[23];
  const float* bev    = (const float*)d_in[24];
  const float* We1    = (const float*)d_in[25];
  const float* be1    = (const float*)d_in[26];
  const float* We2    = (const float*)d_in[27];
  const float* be2    = (const float*)d_in[28];
  const float* ln2_s  = (const float*)d_in[29];
  const float* ln2_b  = (const float*)d_in[30];

  float* ws      = (float*)d_ws;
  float* pos4    = ws;                      // 4*PTOT
  float* xbuf    = pos4 + 4 * PTOT;         // 64*PTOT
  float* qbuf    = xbuf + 64 * PTOT;        // 64*PTOT (qq, then attn-out)
  float* kkv     = qbuf + 64 * PTOT;        // 128*PTOT (kk,v interleaved)
  float* partial = kkv + 128 * PTOT;        // NCL*8*HH
  int*   nidx    = (int*)(partial + NCL * 8 * HH);  // 16*PTOT ints

  k_inproj<<<PTOT / 4, 256, 0, stream>>>(points, w_in, b_in, xbuf, pos4);
  k_knn<<<NCL * 256, 256, 0, stream>>>(pos4, nidx);

  for (int l = 0; l < 3; ++l) {
    k_qkv_gemm<<<PTOT / 32, 256, 0, stream>>>(xbuf, pos4,
        Wq + l * HH * HH, bq + l * HH,
        Wk + l * HH * HH, bk + l * HH,
        Wv + l * HH * HH, bv + l * HH,
        Wpe + l * 3 * HH, bpe + l * HH,
        Wpd + l * 3 * HH, bpd + l * HH,
        qbuf, kkv);
    k_attn_core<<<PTOT / 4, 256, 0, stream>>>(qbuf, kkv, nidx, pos4,
        Wpd + l * 3 * HH, Wa + l * HH, ba + l);
    k_wo_ln<<<PTOT / 32, 256, 0, stream>>>(qbuf,
        Wo + l * HH * HH, bo + l * HH, xbuf,
        ln_s + l * HH, ln_b + l * HH);
  }

  k_pool1<<<NCL * 8, 256, 0, stream>>>(xbuf, partial);
  k_enc<<<4, 512, 0, stream>>>(partial, Wek, bek, Weq, beq, Wev, bev,
                               We1, be1, We2, be2, ln2_s, ln2_b, (float*)d_out);
}

// Round 5
// 283.792 us; speedup vs baseline: 3.5125x; 1.2717x over previous
//
#include <hip/hip_runtime.h>
#include <cfloat>
#include <cmath>
#include <cstdint>

#define NPT   1024          // points per cloud
#define NCL   32            // clouds (B*S)
#define PTOT  32768         // total points
#define HH    64
#define KNN_K 16

#define RFL(x) __builtin_amdgcn_readfirstlane(x)

__device__ __forceinline__ float wave_sum64(float t) {
#pragma unroll
  for (int o = 32; o > 0; o >>= 1) t += __shfl_xor(t, o, 64);
  return t;
}

// Multi-value butterfly reduction: NV (power of 2) values per lane, summed
// across all 64 lanes. Returns: lane l holds the full sum of value (l & (NV-1)),
// replicated in every 16-lane (NV=16) / 8-lane (NV=8) group.
template <int NV>
__device__ __forceinline__ float mreduce(const float (&P)[NV], int lane) {
  float buf[NV];
#pragma unroll
  for (int i = 0; i < NV; ++i) buf[i] = P[i];
#pragma unroll
  for (int s = 0; (1 << s) < NV; ++s) {
    bool hi = (lane & (1 << s)) != 0;
#pragma unroll
    for (int m = 0; m < (NV >> (s + 1)); ++m) {
      float a = buf[2 * m], b = buf[2 * m + 1];
      float keep = hi ? b : a;
      float send = hi ? a : b;
      buf[m] = keep + __shfl_xor(send, 1 << s, 64);
    }
  }
  float t = buf[0];
#pragma unroll
  for (int o = NV; o < 64; o <<= 1) t += __shfl_xor(t, o, 64);
  return t;
}

__device__ __forceinline__ double dshfl_xor(double v, int m) {
  union { double d; int i[2]; } u;
  u.d = v;
  u.i[0] = __shfl_xor(u.i[0], m, 64);
  u.i[1] = __shfl_xor(u.i[1], m, 64);
  return u.d;
}

__device__ __forceinline__ float gelu_f(float z) {
  float zc = 0.7978845608028654f * (z + 0.044715f * z * z * z);
  float t = __expf(2.0f * zc);
  float th = 1.0f - 2.0f / (t + 1.0f);
  return 0.5f * z * (1.0f + th);
}

// ---------------- K0: input projection + pos4 extract -----------------------
__global__ void k_inproj(const float* __restrict__ pts,
                         const float* __restrict__ w_in,
                         const float* __restrict__ b_in,
                         float* __restrict__ x, float* __restrict__ pos4) {
  int p = blockIdx.x * 4 + (threadIdx.x >> 6);
  int h = threadIdx.x & 63;
  const float* pp = pts + p * 6;
  float acc = b_in[h];
#pragma unroll
  for (int f = 0; f < 6; ++f) acc += pp[f] * w_in[f * HH + h];
  x[p * HH + h] = acc;
  if (h < 4) pos4[p * 4 + h] = (h < 3) ? pp[h] : 0.0f;
}

// ---------------- K1: 16-NN via bitonic top-k on f64-packed keys ------------
__global__ __launch_bounds__(256) void k_knn(const float* __restrict__ pos4,
                                             int* __restrict__ nidx) {
  __shared__ float sx[NPT], sy[NPT], sz[NPT];
  int cloud = blockIdx.x >> 8;            // 256 blocks per cloud
  int qbase = (blockIdx.x & 255) * 4;     // 4 queries (waves) per block
  const float4* cp4 = reinterpret_cast<const float4*>(pos4) + cloud * NPT;
  for (int j = threadIdx.x; j < NPT; j += 256) {
    float4 v = cp4[j];
    sx[j] = v.x; sy[j] = v.y; sz[j] = v.z;
  }
  __syncthreads();

  int wv = threadIdx.x >> 6;
  int lane = threadIdx.x & 63;
  int i = qbase + wv;                     // query index within cloud
  float qx = sx[i], qy = sy[i], qz = sz[i];

  double m[16];
#pragma unroll
  for (int c = 0; c < 16; ++c) {
    int j = c * 64 + lane;
    float dx = qx - sx[j], dy = qy - sy[j], dz = qz - sz[j];
    float d2 = __fadd_rn(__fadd_rn(__fmul_rn(dx, dx), __fmul_rn(dy, dy)),
                         __fmul_rn(dz, dz));
    uint64_t key = (1ULL << 62) | ((uint64_t)__float_as_uint(d2) << 20)
                 | (uint64_t)j;
    m[c] = __longlong_as_double((long long)key);
  }

  // per-lane bitonic sort of 16, ascending
#pragma unroll
  for (int k = 2; k <= 16; k <<= 1) {
#pragma unroll
    for (int j = k >> 1; j > 0; j >>= 1) {
#pragma unroll
      for (int a = 0; a < 16; ++a) {
        int b = a ^ j;
        if (b > a) {
          double lo = fmin(m[a], m[b]);
          double hi = fmax(m[a], m[b]);
          bool up = (a & k) == 0;
          m[a] = up ? lo : hi;
          m[b] = up ? hi : lo;
        }
      }
    }
  }

  // 6 cross-lane butterfly merge levels
#pragma unroll
  for (int w = 1; w <= 32; w <<= 1) {
    double t[16];
#pragma unroll
    for (int a = 0; a < 16; ++a) t[a] = dshfl_xor(m[15 - a], w);
#pragma unroll
    for (int a = 0; a < 16; ++a) m[a] = fmin(m[a], t[a]);
#pragma unroll
    for (int j = 8; j > 0; j >>= 1) {
#pragma unroll
      for (int a = 0; a < 16; ++a) {
        int b = a ^ j;
        if (b > a) {
          double lo = fmin(m[a], m[b]);
          m[b] = fmax(m[a], m[b]);
          m[a] = lo;
        }
      }
    }
  }

  if (lane == 0) {
    int obase = (cloud * NPT + i) * KNN_K;
    int4* o = reinterpret_cast<int4*>(nidx + obase);
#pragma unroll
    for (int g = 0; g < 4; ++g) {
      int4 r;
      r.x = (int)(__double_as_longlong(m[g * 4 + 0]) & 1023);
      r.y = (int)(__double_as_longlong(m[g * 4 + 1]) & 1023);
      r.z = (int)(__double_as_longlong(m[g * 4 + 2]) & 1023);
      r.w = (int)(__double_as_longlong(m[g * 4 + 3]) & 1023);
      o[g] = r;
    }
  }
}

// ---------------- K2: register-tiled qkv GEMM with pe/pd folding ------------
__global__ __launch_bounds__(256) void k_qkv_gemm(
    const float* __restrict__ x, const float* __restrict__ pos4,
    const float* __restrict__ Wq, const float* __restrict__ bq,
    const float* __restrict__ Wk, const float* __restrict__ bk,
    const float* __restrict__ Wv, const float* __restrict__ bv,
    const float* __restrict__ Wpe, const float* __restrict__ bpe,
    const float* __restrict__ Wpd, const float* __restrict__ bpd,
    float* __restrict__ qq, float* __restrict__ kkv) {
  int lane = threadIdx.x & 63;
  int pb = RFL(blockIdx.x * 32 + (threadIdx.x >> 6) * 8);
  const float* xw = x + (size_t)pb * HH;
  const float4* posw = reinterpret_cast<const float4*>(pos4) + pb;

  float wpe0 = Wpe[lane], wpe1 = Wpe[HH + lane], wpe2 = Wpe[2 * HH + lane];
  float wpd0 = Wpd[lane], wpd1 = Wpd[HH + lane], wpd2 = Wpd[2 * HH + lane];
  float we0 = wpe0 + wpd0, we1 = wpe1 + wpd1, we2 = wpe2 + wpd2;
  float bqq = bq[lane] + bpe[lane];
  float bkk = bk[lane] + bpe[lane] + bpd[lane];
  float bvv = bv[lane];

  float aq[8], ak[8], av[8];
#pragma unroll
  for (int p = 0; p < 8; ++p) { aq[p] = bqq; ak[p] = bkk; av[p] = bvv; }

#pragma unroll
  for (int c = 0; c < 8; ++c) {
    float wq8[8], wk8[8], wv8[8];
#pragma unroll
    for (int j = 0; j < 8; ++j) {
      int g = c * 8 + j;
      wq8[j] = Wq[g * HH + lane];
      wk8[j] = Wk[g * HH + lane];
      wv8[j] = Wv[g * HH + lane];
    }
#pragma unroll
    for (int p = 0; p < 8; ++p) {
#pragma unroll
      for (int j = 0; j < 8; ++j) {
        float xv = xw[p * HH + c * 8 + j];   // wave-uniform -> scalar load
        aq[p] = fmaf(xv, wq8[j], aq[p]);
        ak[p] = fmaf(xv, wk8[j], ak[p]);
        av[p] = fmaf(xv, wv8[j], av[p]);
      }
    }
  }

#pragma unroll
  for (int p = 0; p < 8; ++p) {
    float4 pp = posw[p];
    float qv = aq[p] + pp.x * wpe0 + pp.y * wpe1 + pp.z * wpe2;
    float kv = ak[p] + pp.x * we0 + pp.y * we1 + pp.z * we2;
    qq[(size_t)(pb + p) * HH + lane] = qv;
    reinterpret_cast<float2*>(kkv + ((size_t)(pb + p) << 7))[lane] =
        make_float2(kv, av[p]);
  }
}

// ---------------- K3: attention core — transposed multi-reduce --------------
__global__ __launch_bounds__(256) void k_attn_core(
    float* __restrict__ qq, const float* __restrict__ kkv,
    const int* __restrict__ nidx, const float* __restrict__ pos4,
    const float* __restrict__ Wpd, const float* __restrict__ Wa,
    const float* __restrict__ ba) {
  int lane = threadIdx.x & 63;
  int bid = blockIdx.x;
  int vb = (bid & 7) * (PTOT / 4 / 8) + (bid >> 3);   // XCD-chunked remap
  int pu = RFL(vb * 4 + (threadIdx.x >> 6));
  int cbase = pu & ~(NPT - 1);

  float4 pp = reinterpret_cast<const float4*>(pos4)[pu];
  float u = qq[(size_t)pu * HH + lane] * Wa[lane] * 0.125f;
  float pdq = pp.x * Wpd[lane] + pp.y * Wpd[HH + lane] + pp.z * Wpd[2 * HH + lane];
  float C0 = wave_sum64(u * pdq) - ba[0];

  const int4* niw = reinterpret_cast<const int4*>(nidx + (size_t)pu * KNN_K);
  int nj[KNN_K];
#pragma unroll
  for (int g = 0; g < 4; ++g) {
    int4 r = niw[g];
    nj[g * 4 + 0] = r.x; nj[g * 4 + 1] = r.y;
    nj[g * 4 + 2] = r.z; nj[g * 4 + 3] = r.w;
  }

  float vj[KNN_K], P[KNN_K];
#pragma unroll
  for (int jj = 0; jj < KNN_K; ++jj) {
    float2 kv = reinterpret_cast<const float2*>(
        kkv + ((size_t)(cbase + nj[jj]) << 7))[lane];
    vj[jj] = kv.y;
    P[jj] = u * kv.x;
  }

  // lane l ends holding full logit for jj = l & 15
  float T = mreduce<16>(P, lane);
  float lg = T - C0;

  // softmax across the 16-group (each group holds all 16 logits)
  float mx = lg;
#pragma unroll
  for (int o = 1; o < 16; o <<= 1) mx = fmaxf(mx, __shfl_xor(mx, o, 64));
  float e = __expf(lg - mx);
  float s = e;
#pragma unroll
  for (int o = 1; o < 16; o <<= 1) s += __shfl_xor(s, o, 64);

  float oacc = 0.f;
  int sb = lane & 48;
#pragma unroll
  for (int jj = 0; jj < KNN_K; ++jj)
    oacc = fmaf(__shfl(e, sb | jj, 64), vj[jj], oacc);

  qq[(size_t)pu * HH + lane] = oacc / s;
}

// ---------------- K4: Wo GEMM + gelu + residual + LN (multi-reduce LN) ------
__global__ __launch_bounds__(256) void k_wo_ln(
    const float* __restrict__ outb, const float* __restrict__ Wo,
    const float* __restrict__ bo, float* __restrict__ x,
    const float* __restrict__ ln_s, const float* __restrict__ ln_b) {
  int lane = threadIdx.x & 63;
  int pb = RFL(blockIdx.x * 32 + (threadIdx.x >> 6) * 8);
  const float* ow = outb + (size_t)pb * HH;

  float acc[8];
  float b0 = bo[lane];
#pragma unroll
  for (int p = 0; p < 8; ++p) acc[p] = b0;

#pragma unroll
  for (int c = 0; c < 8; ++c) {
    float w8[8];
#pragma unroll
    for (int j = 0; j < 8; ++j) w8[j] = Wo[(c * 8 + j) * HH + lane];
#pragma unroll
    for (int p = 0; p < 8; ++p) {
#pragma unroll
      for (int j = 0; j < 8; ++j) {
        float ov = ow[p * HH + c * 8 + j];   // wave-uniform -> scalar load
        acc[p] = fmaf(ov, w8[j], acc[p]);
      }
    }
  }

  float sg = ln_s[lane], bg = ln_b[lane];
  float xn[8];
#pragma unroll
  for (int p = 0; p < 8; ++p)
    xn[p] = x[(size_t)(pb + p) * HH + lane] + gelu_f(acc[p]);

  float Ts = mreduce<8>(xn, lane);            // lane holds sum for p = lane&7
  float dd[8], sq[8];
#pragma unroll
  for (int p = 0; p < 8; ++p) {
    float mu = __shfl(Ts, p, 64) * (1.0f / HH);
    dd[p] = xn[p] - mu;
    sq[p] = dd[p] * dd[p];
  }
  float Tv = mreduce<8>(sq, lane);
#pragma unroll
  for (int p = 0; p < 8; ++p) {
    float var = __shfl(Tv, p, 64) * (1.0f / HH);
    x[(size_t)(pb + p) * HH + lane] = dd[p] * rsqrtf(var + 1e-6f) * sg + bg;
  }
}

// ---------------- K5: partial max over N (stage 1: 128 rows/block) ----------
__global__ __launch_bounds__(256) void k_pool1(const float* __restrict__ x,
                                               float* __restrict__ partial) {
  __shared__ float red[4][HH];
  int cloud = blockIdx.x >> 3, chunk = blockIdx.x & 7;
  int lane = threadIdx.x & 63, wv = threadIdx.x >> 6;
  const float* xp = x + ((size_t)cloud * NPT + chunk * 128 + wv * 32) * HH;
  float mx = -FLT_MAX;
#pragma unroll 8
  for (int n = 0; n < 32; ++n) mx = fmaxf(mx, xp[n * HH + lane]);
  red[wv][lane] = mx;
  __syncthreads();
  if (wv == 0) {
    mx = fmaxf(fmaxf(red[0][lane], red[1][lane]),
               fmaxf(red[2][lane], red[3][lane]));
    partial[(size_t)blockIdx.x * HH + lane] = mx;
  }
}

// ---------------- K6: fused pool-finish + set-encoder + final LN + max ------
__global__ __launch_bounds__(512) void k_enc(
    const float* __restrict__ partial,
    const float* __restrict__ Wek, const float* __restrict__ bek,
    const float* __restrict__ Weq, const float* __restrict__ beq,
    const float* __restrict__ Wev, const float* __restrict__ bev,
    const float* __restrict__ We1, const float* __restrict__ be1,
    const float* __restrict__ We2, const float* __restrict__ be2,
    const float* __restrict__ ln2_s, const float* __restrict__ ln2_b,
    float* __restrict__ out) {
  __shared__ float xs[8][HH], ks[8][HH], vs[8][HH], x2[8][HH];
  int b = blockIdx.x;
  int t = threadIdx.x >> 6;     // token (cloud-in-batch) 0..7
  int h = threadIdx.x & 63;
  {
    const float* pp = partial + ((size_t)(b * 8 + t) * 8) * HH + h;
    float mx = pp[0];
#pragma unroll
    for (int c8 = 1; c8 < 8; ++c8) mx = fmaxf(mx, pp[c8 * HH]);
    xs[t][h] = mx;
  }
  __syncthreads();

  float kk = bek[h], qq = beq[h], vv = bev[h];
#pragma unroll 8
  for (int g = 0; g < HH; ++g) {
    float xv = xs[t][g];
    kk += xv * Wek[g * HH + h];
    qq += xv * Weq[g * HH + h];
    vv += xv * Wev[g * HH + h];
  }
  ks[t][h] = kk;
  vs[t][h] = vv;
  __syncthreads();

  float logit[8];
#pragma unroll
  for (int s = 0; s < 8; ++s) {
    float tt = qq * ks[s][h];
    logit[s] = wave_sum64(tt) * 0.125f;
  }
  float m = logit[0];
#pragma unroll
  for (int s = 1; s < 8; ++s) m = fmaxf(m, logit[s]);
  float ssum = 0.f;
#pragma unroll
  for (int s = 0; s < 8; ++s) { logit[s] = expf(logit[s] - m); ssum += logit[s]; }
  float o = 0.f;
#pragma unroll
  for (int s = 0; s < 8; ++s) o += (logit[s] / ssum) * vs[s][h];

  float h1 = be1[h];
#pragma unroll 8
  for (int g = 0; g < HH; ++g) h1 += __shfl(o, g, 64) * We1[g * HH + h];
  h1 = gelu_f(h1);
  float h2 = be2[h];
#pragma unroll 8
  for (int g = 0; g < HH; ++g) h2 += __shfl(h1, g, 64) * We2[g * HH + h];

  float xn = xs[t][h] + h2;
  float mu = wave_sum64(xn) * (1.0f / HH);
  float d = xn - mu;
  float var = wave_sum64(d * d) * (1.0f / HH);
  float yv = d * rsqrtf(var + 1e-6f) * ln2_s[h] + ln2_b[h];
  x2[t][h] = yv;
  __syncthreads();
  if (t == 0) {
    float mm = x2[0][h];
#pragma unroll
    for (int s = 1; s < 8; ++s) mm = fmaxf(mm, x2[s][h]);
    out[b * HH + h] = mm;
  }
}

// ---------------------------------------------------------------------------
extern "C" void kernel_launch(void* const* d_in, const int* in_sizes, int n_in,
                              void* d_out, int out_size, void* d_ws, size_t ws_size,
                              hipStream_t stream) {
  const float* points = (const float*)d_in[0];
  const float* w_in   = (const float*)d_in[1];
  const float* b_in   = (const float*)d_in[2];
  const float* Wq     = (const float*)d_in[3];
  const float* bq     = (const float*)d_in[4];
  const float* Wk     = (const float*)d_in[5];
  const float* bk     = (const float*)d_in[6];
  const float* Wv     = (const float*)d_in[7];
  const float* bv     = (const float*)d_in[8];
  const float* Wpe    = (const float*)d_in[9];
  const float* bpe    = (const float*)d_in[10];
  const float* Wpd    = (const float*)d_in[11];
  const float* bpd    = (const float*)d_in[12];
  const float* Wa     = (const float*)d_in[13];
  const float* ba     = (const float*)d_in[14];
  const float* Wo     = (const float*)d_in[15];
  const float* bo     = (const float*)d_in[16];
  const float* ln_s   = (const float*)d_in[17];
  const float* ln_b   = (const float*)d_in[18];
  const float* Wek    = (const float*)d_in[19];
  const float* bek    = (const float*)d_in[20];
  const float* Weq    = (const float*)d_in[21];
  const float* beq    = (const float*)d_in[22];
  const float* Wev    = (const float*)d_in[23];
  const float* bev    = (const float*)d_in[24];
  const float* We1    = (const float*)d_in[25];
  const float* be1    = (const float*)d_in[26];
  const float* We2    = (const float*)d_in[27];
  const float* be2    = (const float*)d_in[28];
  const float* ln2_s  = (const float*)d_in[29];
  const float* ln2_b  = (const float*)d_in[30];

  float* ws      = (float*)d_ws;
  float* pos4    = ws;                      // 4*PTOT
  float* xbuf    = pos4 + 4 * PTOT;         // 64*PTOT
  float* qbuf    = xbuf + 64 * PTOT;        // 64*PTOT (qq, then attn-out)
  float* kkv     = qbuf + 64 * PTOT;        // 128*PTOT (kk,v interleaved)
  float* partial = kkv + 128 * PTOT;        // NCL*8*HH
  int*   nidx    = (int*)(partial + NCL * 8 * HH);  // 16*PTOT ints

  k_inproj<<<PTOT / 4, 256, 0, stream>>>(points, w_in, b_in, xbuf, pos4);
  k_knn<<<NCL * 256, 256, 0, stream>>>(pos4, nidx);

  for (int l = 0; l < 3; ++l) {
    k_qkv_gemm<<<PTOT / 32, 256, 0, stream>>>(xbuf, pos4,
        Wq + l * HH * HH, bq + l * HH,
        Wk + l * HH * HH, bk + l * HH,
        Wv + l * HH * HH, bv + l * HH,
        Wpe + l * 3 * HH, bpe + l * HH,
        Wpd + l * 3 * HH, bpd + l * HH,
        qbuf, kkv);
    k_attn_core<<<PTOT / 4, 256, 0, stream>>>(qbuf, kkv, nidx, pos4,
        Wpd + l * 3 * HH, Wa + l * HH, ba + l);
    k_wo_ln<<<PTOT / 32, 256, 0, stream>>>(qbuf,
        Wo + l * HH * HH, bo + l * HH, xbuf,
        ln_s + l * HH, ln_b + l * HH);
  }

  k_pool1<<<NCL * 8, 256, 0, stream>>>(xbuf, partial);
  k_enc<<<4, 512, 0, stream>>>(partial, Wek, bek, Weq, beq, Wev, bev,
                               We1, be1, We2, be2, ln2_s, ln2_b, (float*)d_out);
}

// Round 6
// 268.030 us; speedup vs baseline: 3.7191x; 1.0588x over previous
//
#include <hip/hip_runtime.h>
#include <cfloat>
#include <cmath>
#include <cstdint>

#define NPT   1024          // points per cloud
#define NCL   32            // clouds (B*S)
#define PTOT  32768         // total points
#define HH    64
#define KNN_K 16
#define KNN_BLKS (NCL * 256)   // 8192: 4 queries per block

#define RFL(x) __builtin_amdgcn_readfirstlane(x)

__device__ __forceinline__ float wave_sum64(float t) {
#pragma unroll
  for (int o = 32; o > 0; o >>= 1) t += __shfl_xor(t, o, 64);
  return t;
}

// Multi-value butterfly reduction: NV values/lane summed across 64 lanes.
// Lane l ends holding the full sum of value (l & (NV-1)).
template <int NV>
__device__ __forceinline__ float mreduce(const float (&P)[NV], int lane) {
  float buf[NV];
#pragma unroll
  for (int i = 0; i < NV; ++i) buf[i] = P[i];
#pragma unroll
  for (int s = 0; (1 << s) < NV; ++s) {
    bool hi = (lane & (1 << s)) != 0;
#pragma unroll
    for (int m = 0; m < (NV >> (s + 1)); ++m) {
      float a = buf[2 * m], b = buf[2 * m + 1];
      float keep = hi ? b : a;
      float send = hi ? a : b;
      buf[m] = keep + __shfl_xor(send, 1 << s, 64);
    }
  }
  float t = buf[0];
#pragma unroll
  for (int o = NV; o < 64; o <<= 1) t += __shfl_xor(t, o, 64);
  return t;
}

__device__ __forceinline__ float gelu_f(float z) {
  float zc = 0.7978845608028654f * (z + 0.044715f * z * z * z);
  float t = __expf(2.0f * zc);
  float th = 1.0f - 2.0f / (t + 1.0f);
  return 0.5f * z * (1.0f + th);
}

// ---------------- K0: fused [knn-select | input projection] ----------------
// Blocks [0, KNN_BLKS): 16-NN set-selection via bitwise binary search.
// Blocks [KNN_BLKS, +PTOT/4): input projection + pos4 extract.
// No dependency between halves (knn reads pts directly).
__global__ __launch_bounds__(256) void k_front(
    const float* __restrict__ pts, const float* __restrict__ w_in,
    const float* __restrict__ b_in, float* __restrict__ x,
    float* __restrict__ pos4, int* __restrict__ nidx) {
  if (blockIdx.x >= KNN_BLKS) {
    // ---- input projection role ----
    int p = (blockIdx.x - KNN_BLKS) * 4 + (threadIdx.x >> 6);
    int h = threadIdx.x & 63;
    const float* pp = pts + p * 6;
    float acc = b_in[h];
#pragma unroll
    for (int f = 0; f < 6; ++f) acc += pp[f] * w_in[f * HH + h];
    x[p * HH + h] = acc;
    if (h < 4) pos4[p * 4 + h] = (h < 3) ? pp[h] : 0.0f;
    return;
  }

  // ---- knn role: 4 queries (one per wave) ----
  __shared__ float sx[NPT], sy[NPT], sz[NPT];
  int cloud = blockIdx.x >> 8;
  int qbase = (blockIdx.x & 255) * 4;
  const float* cp = pts + (size_t)cloud * NPT * 6;
  for (int j = threadIdx.x; j < NPT; j += 256) {
    sx[j] = cp[j * 6 + 0];
    sy[j] = cp[j * 6 + 1];
    sz[j] = cp[j * 6 + 2];
  }
  __syncthreads();

  int wv = threadIdx.x >> 6;
  int lane = threadIdx.x & 63;
  int i = qbase + wv;
  float qx = sx[i], qy = sy[i], qz = sz[i];

  // d2 >= 0 -> float bits are order-isomorphic to u32
  unsigned du[16];
#pragma unroll
  for (int c = 0; c < 16; ++c) {
    int j = c * 64 + lane;
    float dx = qx - sx[j], dy = qy - sy[j], dz = qz - sz[j];
    // exact IEEE, reference order, no fma contraction
    float d2 = __fadd_rn(__fadd_rn(__fmul_rn(dx, dx), __fmul_rn(dy, dy)),
                         __fmul_rn(dz, dz));
    du[c] = __float_as_uint(d2);
  }

  // greedy MSB->LSB: t ends as max v with count(du < v) <= 15, i.e. the
  // exact 16th-smallest value (bits) among the 1024 candidates.
  unsigned t = 0u;
  for (int bit = 30; bit >= 0; --bit) {
    unsigned tp = t | (1u << bit);
    int cnt = 0;
#pragma unroll
    for (int c = 0; c < 16; ++c)
      cnt += __popcll(__ballot(du[c] < tp));
    if (cnt <= 15) t = tp;
  }

  // collect strict-less survivors (count = L <= 15), slots via ballot prefix
  int obase = (cloud * NPT + i) * KNN_K;
  unsigned long long below = (1ull << lane) - 1ull;
  int slot = 0;
#pragma unroll
  for (int c = 0; c < 16; ++c) {
    bool lt = du[c] < t;
    unsigned long long m = __ballot(lt);
    if (lt) {
      int off = __popcll(m & below);
      nidx[obase + slot + off] = c * 64 + lane;
    }
    slot += __popcll(m);
  }

  // ties at t: take lowest global indices j = c*64+lane (c-major = j order)
  int erem = KNN_K - slot;
#pragma unroll
  for (int c = 0; c < 16; ++c) {
    if (erem > 0) {
      bool eq = du[c] == t;
      unsigned long long m = __ballot(eq);
      int cnt = __popcll(m);
      int take = cnt < erem ? cnt : erem;
      if (eq) {
        int off = __popcll(m & below);
        if (off < take) nidx[obase + slot + off] = c * 64 + lane;
      }
      slot += take;
      erem -= take;
    }
  }
}

// ---------------- K2: register-tiled qkv GEMM with pe/pd folding ------------
__global__ __launch_bounds__(256) void k_qkv_gemm(
    const float* __restrict__ x, const float* __restrict__ pos4,
    const float* __restrict__ Wq, const float* __restrict__ bq,
    const float* __restrict__ Wk, const float* __restrict__ bk,
    const float* __restrict__ Wv, const float* __restrict__ bv,
    const float* __restrict__ Wpe, const float* __restrict__ bpe,
    const float* __restrict__ Wpd, const float* __restrict__ bpd,
    float* __restrict__ qq, float* __restrict__ kkv) {
  int lane = threadIdx.x & 63;
  int pb = RFL(blockIdx.x * 32 + (threadIdx.x >> 6) * 8);
  const float* xw = x + (size_t)pb * HH;
  const float4* posw = reinterpret_cast<const float4*>(pos4) + pb;

  float wpe0 = Wpe[lane], wpe1 = Wpe[HH + lane], wpe2 = Wpe[2 * HH + lane];
  float wpd0 = Wpd[lane], wpd1 = Wpd[HH + lane], wpd2 = Wpd[2 * HH + lane];
  float we0 = wpe0 + wpd0, we1 = wpe1 + wpd1, we2 = wpe2 + wpd2;
  float bqq = bq[lane] + bpe[lane];
  float bkk = bk[lane] + bpe[lane] + bpd[lane];
  float bvv = bv[lane];

  float aq[8], ak[8], av[8];
#pragma unroll
  for (int p = 0; p < 8; ++p) { aq[p] = bqq; ak[p] = bkk; av[p] = bvv; }

#pragma unroll
  for (int c = 0; c < 8; ++c) {
    float wq8[8], wk8[8], wv8[8];
#pragma unroll
    for (int j = 0; j < 8; ++j) {
      int g = c * 8 + j;
      wq8[j] = Wq[g * HH + lane];
      wk8[j] = Wk[g * HH + lane];
      wv8[j] = Wv[g * HH + lane];
    }
#pragma unroll
    for (int p = 0; p < 8; ++p) {
#pragma unroll
      for (int j = 0; j < 8; ++j) {
        float xv = xw[p * HH + c * 8 + j];   // wave-uniform -> scalar load
        aq[p] = fmaf(xv, wq8[j], aq[p]);
        ak[p] = fmaf(xv, wk8[j], ak[p]);
        av[p] = fmaf(xv, wv8[j], av[p]);
      }
    }
  }

#pragma unroll
  for (int p = 0; p < 8; ++p) {
    float4 pp = posw[p];
    float qv = aq[p] + pp.x * wpe0 + pp.y * wpe1 + pp.z * wpe2;
    float kv = ak[p] + pp.x * we0 + pp.y * we1 + pp.z * we2;
    qq[(size_t)(pb + p) * HH + lane] = qv;
    reinterpret_cast<float2*>(kkv + ((size_t)(pb + p) << 7))[lane] =
        make_float2(kv, av[p]);
  }
}

// ---------------- K3: attention core — transposed multi-reduce --------------
__global__ __launch_bounds__(256) void k_attn_core(
    float* __restrict__ qq, const float* __restrict__ kkv,
    const int* __restrict__ nidx, const float* __restrict__ pos4,
    const float* __restrict__ Wpd, const float* __restrict__ Wa,
    const float* __restrict__ ba) {
  int lane = threadIdx.x & 63;
  int bid = blockIdx.x;
  int vb = (bid & 7) * (PTOT / 4 / 8) + (bid >> 3);   // XCD-chunked remap
  int pu = RFL(vb * 4 + (threadIdx.x >> 6));
  int cbase = pu & ~(NPT - 1);

  float4 pp = reinterpret_cast<const float4*>(pos4)[pu];
  float u = qq[(size_t)pu * HH + lane] * Wa[lane] * 0.125f;
  float pdq = pp.x * Wpd[lane] + pp.y * Wpd[HH + lane] + pp.z * Wpd[2 * HH + lane];
  float C0 = wave_sum64(u * pdq) - ba[0];

  const int4* niw = reinterpret_cast<const int4*>(nidx + (size_t)pu * KNN_K);
  int nj[KNN_K];
#pragma unroll
  for (int g = 0; g < 4; ++g) {
    int4 r = niw[g];
    nj[g * 4 + 0] = r.x; nj[g * 4 + 1] = r.y;
    nj[g * 4 + 2] = r.z; nj[g * 4 + 3] = r.w;
  }

  float vj[KNN_K], P[KNN_K];
#pragma unroll
  for (int jj = 0; jj < KNN_K; ++jj) {
    float2 kv = reinterpret_cast<const float2*>(
        kkv + ((size_t)(cbase + nj[jj]) << 7))[lane];
    vj[jj] = kv.y;
    P[jj] = u * kv.x;
  }

  // lane l ends holding full logit for jj = l & 15
  float T = mreduce<16>(P, lane);
  float lg = T - C0;

  float mx = lg;
#pragma unroll
  for (int o = 1; o < 16; o <<= 1) mx = fmaxf(mx, __shfl_xor(mx, o, 64));
  float e = __expf(lg - mx);
  float s = e;
#pragma unroll
  for (int o = 1; o < 16; o <<= 1) s += __shfl_xor(s, o, 64);

  float oacc = 0.f;
  int sb = lane & 48;
#pragma unroll
  for (int jj = 0; jj < KNN_K; ++jj)
    oacc = fmaf(__shfl(e, sb | jj, 64), vj[jj], oacc);

  qq[(size_t)pu * HH + lane] = oacc / s;
}

// ---------------- K4: Wo GEMM + gelu + residual + LN (+optional pool) -------
__global__ __launch_bounds__(256) void k_wo_ln(
    const float* __restrict__ outb, const float* __restrict__ Wo,
    const float* __restrict__ bo, float* __restrict__ x,
    const float* __restrict__ ln_s, const float* __restrict__ ln_b,
    float* __restrict__ partial, int do_pool) {
  __shared__ float red[4][HH];
  int lane = threadIdx.x & 63;
  int wv = threadIdx.x >> 6;
  int pb = RFL(blockIdx.x * 32 + wv * 8);
  const float* ow = outb + (size_t)pb * HH;

  float acc[8];
  float b0 = bo[lane];
#pragma unroll
  for (int p = 0; p < 8; ++p) acc[p] = b0;

#pragma unroll
  for (int c = 0; c < 8; ++c) {
    float w8[8];
#pragma unroll
    for (int j = 0; j < 8; ++j) w8[j] = Wo[(c * 8 + j) * HH + lane];
#pragma unroll
    for (int p = 0; p < 8; ++p) {
#pragma unroll
      for (int j = 0; j < 8; ++j) {
        float ov = ow[p * HH + c * 8 + j];   // wave-uniform -> scalar load
        acc[p] = fmaf(ov, w8[j], acc[p]);
      }
    }
  }

  float sg = ln_s[lane], bg = ln_b[lane];
  float xn[8];
#pragma unroll
  for (int p = 0; p < 8; ++p)
    xn[p] = x[(size_t)(pb + p) * HH + lane] + gelu_f(acc[p]);

  float Ts = mreduce<8>(xn, lane);
  float dd[8], sq[8];
#pragma unroll
  for (int p = 0; p < 8; ++p) {
    float mu = __shfl(Ts, p, 64) * (1.0f / HH);
    dd[p] = xn[p] - mu;
    sq[p] = dd[p] * dd[p];
  }
  float Tv = mreduce<8>(sq, lane);
  float mxp = -FLT_MAX;
#pragma unroll
  for (int p = 0; p < 8; ++p) {
    float var = __shfl(Tv, p, 64) * (1.0f / HH);
    float yv = dd[p] * rsqrtf(var + 1e-6f) * sg + bg;
    x[(size_t)(pb + p) * HH + lane] = yv;
    mxp = fmaxf(mxp, yv);
  }

  if (do_pool) {   // last layer: per-block (32-point) partial max
    red[wv][lane] = mxp;
    __syncthreads();
    if (wv == 0) {
      float m = fmaxf(fmaxf(red[0][lane], red[1][lane]),
                      fmaxf(red[2][lane], red[3][lane]));
      partial[(size_t)blockIdx.x * HH + lane] = m;
    }
  }
}

// ---------------- K6: fused pool-finish + set-encoder + final LN + max ------
__global__ __launch_bounds__(512) void k_enc(
    const float* __restrict__ partial,
    const float* __restrict__ Wek, const float* __restrict__ bek,
    const float* __restrict__ Weq, const float* __restrict__ beq,
    const float* __restrict__ Wev, const float* __restrict__ bev,
    const float* __restrict__ We1, const float* __restrict__ be1,
    const float* __restrict__ We2, const float* __restrict__ be2,
    const float* __restrict__ ln2_s, const float* __restrict__ ln2_b,
    float* __restrict__ out) {
  __shared__ float xs[8][HH], ks[8][HH], vs[8][HH], x2[8][HH];
  int b = blockIdx.x;
  int t = threadIdx.x >> 6;     // token (cloud-in-batch) 0..7
  int h = threadIdx.x & 63;
  {
    int ci = b * 8 + t;
    const float* pp = partial + (size_t)ci * 32 * HH + h;
    float mx = pp[0];
#pragma unroll
    for (int c8 = 1; c8 < 32; ++c8) mx = fmaxf(mx, pp[c8 * HH]);
    xs[t][h] = mx;
  }
  __syncthreads();

  float kk = bek[h], qq = beq[h], vv = bev[h];
#pragma unroll 8
  for (int g = 0; g < HH; ++g) {
    float xv = xs[t][g];
    kk += xv * Wek[g * HH + h];
    qq += xv * Weq[g * HH + h];
    vv += xv * Wev[g * HH + h];
  }
  ks[t][h] = kk;
  vs[t][h] = vv;
  __syncthreads();

  float logit[8];
#pragma unroll
  for (int s = 0; s < 8; ++s) {
    float tt = qq * ks[s][h];
    logit[s] = wave_sum64(tt) * 0.125f;
  }
  float m = logit[0];
#pragma unroll
  for (int s = 1; s < 8; ++s) m = fmaxf(m, logit[s]);
  float ssum = 0.f;
#pragma unroll
  for (int s = 0; s < 8; ++s) { logit[s] = expf(logit[s] - m); ssum += logit[s]; }
  float o = 0.f;
#pragma unroll
  for (int s = 0; s < 8; ++s) o += (logit[s] / ssum) * vs[s][h];

  float h1 = be1[h];
#pragma unroll 8
  for (int g = 0; g < HH; ++g) h1 += __shfl(o, g, 64) * We1[g * HH + h];
  h1 = gelu_f(h1);
  float h2 = be2[h];
#pragma unroll 8
  for (int g = 0; g < HH; ++g) h2 += __shfl(h1, g, 64) * We2[g * HH + h];

  float xn = xs[t][h] + h2;
  float mu = wave_sum64(xn) * (1.0f / HH);
  float d = xn - mu;
  float var = wave_sum64(d * d) * (1.0f / HH);
  float yv = d * rsqrtf(var + 1e-6f) * ln2_s[h] + ln2_b[h];
  x2[t][h] = yv;
  __syncthreads();
  if (t == 0) {
    float mm = x2[0][h];
#pragma unroll
    for (int s = 1; s < 8; ++s) mm = fmaxf(mm, x2[s][h]);
    out[b * HH + h] = mm;
  }
}

// ---------------------------------------------------------------------------
extern "C" void kernel_launch(void* const* d_in, const int* in_sizes, int n_in,
                              void* d_out, int out_size, void* d_ws, size_t ws_size,
                              hipStream_t stream) {
  const float* points = (const float*)d_in[0];
  const float* w_in   = (const float*)d_in[1];
  const float* b_in   = (const float*)d_in[2];
  const float* Wq     = (const float*)d_in[3];
  const float* bq     = (const float*)d_in[4];
  const float* Wk     = (const float*)d_in[5];
  const float* bk     = (const float*)d_in[6];
  const float* Wv     = (const float*)d_in[7];
  const float* bv     = (const float*)d_in[8];
  const float* Wpe    = (const float*)d_in[9];
  const float* bpe    = (const float*)d_in[10];
  const float* Wpd    = (const float*)d_in[11];
  const float* bpd    = (const float*)d_in[12];
  const float* Wa     = (const float*)d_in[13];
  const float* ba     = (const float*)d_in[14];
  const float* Wo     = (const float*)d_in[15];
  const float* bo     = (const float*)d_in[16];
  const float* ln_s   = (const float*)d_in[17];
  const float* ln_b   = (const float*)d_in[18];
  const float* Wek    = (const float*)d_in[19];
  const float* bek    = (const float*)d_in[20];
  const float* Weq    = (const float*)d_in[21];
  const float* beq    = (const float*)d_in[22];
  const float* Wev    = (const float*)d_in[23];
  const float* bev    = (const float*)d_in[24];
  const float* We1    = (const float*)d_in[25];
  const float* be1    = (const float*)d_in[26];
  const float* We2    = (const float*)d_in[27];
  const float* be2    = (const float*)d_in[28];
  const float* ln2_s  = (const float*)d_in[29];
  const float* ln2_b  = (const float*)d_in[30];

  float* ws      = (float*)d_ws;
  float* pos4    = ws;                      // 4*PTOT
  float* xbuf    = pos4 + 4 * PTOT;         // 64*PTOT
  float* qbuf    = xbuf + 64 * PTOT;        // 64*PTOT (qq, then attn-out)
  float* kkv     = qbuf + 64 * PTOT;        // 128*PTOT (kk,v interleaved)
  float* partial = kkv + 128 * PTOT;        // 1024*HH
  int*   nidx    = (int*)(partial + 1024 * HH);  // 16*PTOT ints

  k_front<<<KNN_BLKS + PTOT / 4, 256, 0, stream>>>(points, w_in, b_in,
                                                   xbuf, pos4, nidx);

  for (int l = 0; l < 3; ++l) {
    k_qkv_gemm<<<PTOT / 32, 256, 0, stream>>>(xbuf, pos4,
        Wq + l * HH * HH, bq + l * HH,
        Wk + l * HH * HH, bk + l * HH,
        Wv + l * HH * HH, bv + l * HH,
        Wpe + l * 3 * HH, bpe + l * HH,
        Wpd + l * 3 * HH, bpd + l * HH,
        qbuf, kkv);
    k_attn_core<<<PTOT / 4, 256, 0, stream>>>(qbuf, kkv, nidx, pos4,
        Wpd + l * 3 * HH, Wa + l * HH, ba + l);
    k_wo_ln<<<PTOT / 32, 256, 0, stream>>>(qbuf,
        Wo + l * HH * HH, bo + l * HH, xbuf,
        ln_s + l * HH, ln_b + l * HH, partial, l == 2 ? 1 : 0);
  }

  k_enc<<<4, 512, 0, stream>>>(partial, Wek, bek, Weq, beq, Wev, bev,
                               We1, be1, We2, be2, ln2_s, ln2_b, (float*)d_out);
}

// Round 7
// 239.533 us; speedup vs baseline: 4.1615x; 1.1190x over previous
//
#include <hip/hip_runtime.h>
#include <cfloat>
#include <cmath>
#include <cstdint>

#define NPT   1024          // points per cloud
#define NCL   32            // clouds (B*S)
#define PTOT  32768         // total points
#define HH    64
#define KNN_K 16
#define KNN_BLKS (NCL * 256)   // 8192: 4 queries per block

#define RFL(x) __builtin_amdgcn_readfirstlane(x)

__device__ __forceinline__ float wave_sum64(float t) {
#pragma unroll
  for (int o = 32; o > 0; o >>= 1) t += __shfl_xor(t, o, 64);
  return t;
}

// Multi-value butterfly reduction: NV values/lane summed across 64 lanes.
// Lane l ends holding the full sum of value (l & (NV-1)).
template <int NV>
__device__ __forceinline__ float mreduce(const float (&P)[NV], int lane) {
  float buf[NV];
#pragma unroll
  for (int i = 0; i < NV; ++i) buf[i] = P[i];
#pragma unroll
  for (int s = 0; (1 << s) < NV; ++s) {
    bool hi = (lane & (1 << s)) != 0;
#pragma unroll
    for (int m = 0; m < (NV >> (s + 1)); ++m) {
      float a = buf[2 * m], b = buf[2 * m + 1];
      float keep = hi ? b : a;
      float send = hi ? a : b;
      buf[m] = keep + __shfl_xor(send, 1 << s, 64);
    }
  }
  float t = buf[0];
#pragma unroll
  for (int o = NV; o < 64; o <<= 1) t += __shfl_xor(t, o, 64);
  return t;
}

__device__ __forceinline__ float gelu_f(float z) {
  float zc = 0.7978845608028654f * (z + 0.044715f * z * z * z);
  float t = __expf(2.0f * zc);
  float th = 1.0f - 2.0f / (t + 1.0f);
  return 0.5f * z * (1.0f + th);
}

// ---------------- K0: fused [knn-select | input projection] ----------------
// knn: coarse 16-bit radix search for the boundary bucket, then exact
// wave-min extraction of the tail (ties -> lowest index, == lax.top_k).
__global__ __launch_bounds__(256) void k_front(
    const float* __restrict__ pts, const float* __restrict__ w_in,
    const float* __restrict__ b_in, float* __restrict__ x,
    float* __restrict__ pos4, int* __restrict__ nidx) {
  if (blockIdx.x >= KNN_BLKS) {
    // ---- input projection role ----
    int p = (blockIdx.x - KNN_BLKS) * 4 + (threadIdx.x >> 6);
    int h = threadIdx.x & 63;
    const float* pp = pts + p * 6;
    float acc = b_in[h];
#pragma unroll
    for (int f = 0; f < 6; ++f) acc += pp[f] * w_in[f * HH + h];
    x[p * HH + h] = acc;
    if (h < 4) pos4[p * 4 + h] = (h < 3) ? pp[h] : 0.0f;
    return;
  }

  // ---- knn role: 4 queries (one per wave) ----
  __shared__ float sx[NPT], sy[NPT], sz[NPT];
  int cloud = blockIdx.x >> 8;
  int qbase = (blockIdx.x & 255) * 4;
  const float* cp = pts + (size_t)cloud * NPT * 6;
  for (int j = threadIdx.x; j < NPT; j += 256) {
    sx[j] = cp[j * 6 + 0];
    sy[j] = cp[j * 6 + 1];
    sz[j] = cp[j * 6 + 2];
  }
  __syncthreads();

  int wv = threadIdx.x >> 6;
  int lane = threadIdx.x & 63;
  int i = qbase + wv;
  float qx = sx[i], qy = sy[i], qz = sz[i];

  // d2 >= 0 -> float bits are order-isomorphic to u32
  unsigned du[16];
#pragma unroll
  for (int c = 0; c < 16; ++c) {
    int j = c * 64 + lane;
    float dx = qx - sx[j], dy = qy - sy[j], dz = qz - sz[j];
    // exact IEEE, reference order, no fma contraction
    float d2 = __fadd_rn(__fadd_rn(__fmul_rn(dx, dx), __fmul_rn(dy, dy)),
                         __fmul_rn(dz, dz));
    du[c] = __float_as_uint(d2);
  }

  // coarse greedy MSB->bit15: t = max 2^15-aligned value with count(<t) <= 15
  unsigned t = 0u;
#pragma unroll
  for (int bit = 30; bit >= 15; --bit) {
    unsigned tp = t | (1u << bit);
    int cnt = 0;
#pragma unroll
    for (int c = 0; c < 16; ++c)
      cnt += __popcll(__ballot(du[c] < tp));
    if (cnt <= 15) t = tp;
  }
  // 16th value lies in [t, t + 2^15)

  // collect strict-less survivors (count r <= 15), slots via ballot prefix
  int obase = (cloud * NPT + i) * KNN_K;
  unsigned long long below = (1ull << lane) - 1ull;
  int slot = 0;
#pragma unroll
  for (int c = 0; c < 16; ++c) {
    bool lt = du[c] < t;
    unsigned long long m = __ballot(lt);
    if (lt) {
      int off = __popcll(m & below);
      nidx[obase + slot + off] = c * 64 + lane;
    }
    slot += __popcll(m);
  }

  // exact tail: extract (16 - slot) smallest from the boundary bucket,
  // ties broken by lowest global index (lax.top_k stable semantics)
  int erem = KNN_K - slot;
  unsigned hi_end = t + (1u << 15);
  unsigned bu[16];
#pragma unroll
  for (int c = 0; c < 16; ++c)
    bu[c] = (du[c] >= t && du[c] < hi_end) ? du[c] : 0xFFFFFFFFu;
  for (int r2 = 0; r2 < erem; ++r2) {
    unsigned bd = bu[0];
    int bc = 0;
#pragma unroll
    for (int c = 1; c < 16; ++c) {
      if (bu[c] < bd) { bd = bu[c]; bc = c; }   // strict -> lowest c on tie
    }
    unsigned gd = bd;
#pragma unroll
    for (int o = 32; o > 0; o >>= 1) {
      unsigned g2 = (unsigned)__shfl_xor((int)gd, o, 64);
      gd = (g2 < gd) ? g2 : gd;
    }
    int myidx = bc * 64 + lane;
    int gidx = (bd == gd) ? myidx : 0x7fffffff;
#pragma unroll
    for (int o = 32; o > 0; o >>= 1) {
      int g2 = __shfl_xor(gidx, o, 64);
      gidx = (g2 < gidx) ? g2 : gidx;
    }
    if (lane == 0) nidx[obase + slot + r2] = gidx;
    int sel = (myidx == gidx) ? bc : 99;
#pragma unroll
    for (int c = 0; c < 16; ++c) bu[c] = (c == sel) ? 0xFFFFFFFFu : bu[c];
  }
}

// ---------------- K2: register-tiled qkv GEMM (4 pts/wave) ------------------
__global__ __launch_bounds__(256) void k_qkv_gemm(
    const float* __restrict__ x, const float* __restrict__ pos4,
    const float* __restrict__ Wq, const float* __restrict__ bq,
    const float* __restrict__ Wk, const float* __restrict__ bk,
    const float* __restrict__ Wv, const float* __restrict__ bv,
    const float* __restrict__ Wpe, const float* __restrict__ bpe,
    const float* __restrict__ Wpd, const float* __restrict__ bpd,
    float* __restrict__ qq, float* __restrict__ kkv) {
  int lane = threadIdx.x & 63;
  int pb = RFL(blockIdx.x * 16 + (threadIdx.x >> 6) * 4);
  const float* xw = x + (size_t)pb * HH;
  const float4* posw = reinterpret_cast<const float4*>(pos4) + pb;

  float wpe0 = Wpe[lane], wpe1 = Wpe[HH + lane], wpe2 = Wpe[2 * HH + lane];
  float wpd0 = Wpd[lane], wpd1 = Wpd[HH + lane], wpd2 = Wpd[2 * HH + lane];
  float we0 = wpe0 + wpd0, we1 = wpe1 + wpd1, we2 = wpe2 + wpd2;
  float bqq = bq[lane] + bpe[lane];
  float bkk = bk[lane] + bpe[lane] + bpd[lane];
  float bvv = bv[lane];

  float aq[4], ak[4], av[4];
#pragma unroll
  for (int p = 0; p < 4; ++p) { aq[p] = bqq; ak[p] = bkk; av[p] = bvv; }

#pragma unroll
  for (int c = 0; c < 8; ++c) {
    float wq8[8], wk8[8], wv8[8];
#pragma unroll
    for (int j = 0; j < 8; ++j) {
      int g = c * 8 + j;
      wq8[j] = Wq[g * HH + lane];
      wk8[j] = Wk[g * HH + lane];
      wv8[j] = Wv[g * HH + lane];
    }
#pragma unroll
    for (int p = 0; p < 4; ++p) {
#pragma unroll
      for (int j = 0; j < 8; ++j) {
        float xv = xw[p * HH + c * 8 + j];   // wave-uniform -> scalar load
        aq[p] = fmaf(xv, wq8[j], aq[p]);
        ak[p] = fmaf(xv, wk8[j], ak[p]);
        av[p] = fmaf(xv, wv8[j], av[p]);
      }
    }
  }

#pragma unroll
  for (int p = 0; p < 4; ++p) {
    float4 pp = posw[p];
    float qv = aq[p] + pp.x * wpe0 + pp.y * wpe1 + pp.z * wpe2;
    float kv = ak[p] + pp.x * we0 + pp.y * we1 + pp.z * we2;
    qq[(size_t)(pb + p) * HH + lane] = qv;
    reinterpret_cast<float2*>(kkv + ((size_t)(pb + p) << 7))[lane] =
        make_float2(kv, av[p]);
  }
}

// ---------------- K3: attention core — transposed multi-reduce --------------
__global__ __launch_bounds__(256) void k_attn_core(
    float* __restrict__ qq, const float* __restrict__ kkv,
    const int* __restrict__ nidx, const float* __restrict__ pos4,
    const float* __restrict__ Wpd, const float* __restrict__ Wa,
    const float* __restrict__ ba) {
  int lane = threadIdx.x & 63;
  int bid = blockIdx.x;
  int vb = (bid & 7) * (PTOT / 4 / 8) + (bid >> 3);   // XCD-chunked remap
  int pu = RFL(vb * 4 + (threadIdx.x >> 6));
  int cbase = pu & ~(NPT - 1);

  float4 pp = reinterpret_cast<const float4*>(pos4)[pu];
  float u = qq[(size_t)pu * HH + lane] * Wa[lane] * 0.125f;
  float pdq = pp.x * Wpd[lane] + pp.y * Wpd[HH + lane] + pp.z * Wpd[2 * HH + lane];
  float C0 = wave_sum64(u * pdq) - ba[0];

  const int4* niw = reinterpret_cast<const int4*>(nidx + (size_t)pu * KNN_K);
  int nj[KNN_K];
#pragma unroll
  for (int g = 0; g < 4; ++g) {
    int4 r = niw[g];
    nj[g * 4 + 0] = r.x; nj[g * 4 + 1] = r.y;
    nj[g * 4 + 2] = r.z; nj[g * 4 + 3] = r.w;
  }

  float vj[KNN_K], P[KNN_K];
#pragma unroll
  for (int jj = 0; jj < KNN_K; ++jj) {
    float2 kv = reinterpret_cast<const float2*>(
        kkv + ((size_t)(cbase + nj[jj]) << 7))[lane];
    vj[jj] = kv.y;
    P[jj] = u * kv.x;
  }

  // lane l ends holding full logit for jj = l & 15
  float T = mreduce<16>(P, lane);
  float lg = T - C0;

  float mx = lg;
#pragma unroll
  for (int o = 1; o < 16; o <<= 1) mx = fmaxf(mx, __shfl_xor(mx, o, 64));
  float e = __expf(lg - mx);
  float s = e;
#pragma unroll
  for (int o = 1; o < 16; o <<= 1) s += __shfl_xor(s, o, 64);

  float oacc = 0.f;
  int sb = lane & 48;
#pragma unroll
  for (int jj = 0; jj < KNN_K; ++jj)
    oacc = fmaf(__shfl(e, sb | jj, 64), vj[jj], oacc);

  qq[(size_t)pu * HH + lane] = oacc / s;
}

// ---------------- K4: Wo GEMM + gelu + residual + LN (4 pts/wave) -----------
__global__ __launch_bounds__(256) void k_wo_ln(
    const float* __restrict__ outb, const float* __restrict__ Wo,
    const float* __restrict__ bo, float* __restrict__ x,
    const float* __restrict__ ln_s, const float* __restrict__ ln_b,
    float* __restrict__ partial, int do_pool) {
  __shared__ float red[4][HH];
  int lane = threadIdx.x & 63;
  int wv = threadIdx.x >> 6;
  int pb = RFL(blockIdx.x * 16 + wv * 4);
  const float* ow = outb + (size_t)pb * HH;

  float acc[4];
  float b0 = bo[lane];
#pragma unroll
  for (int p = 0; p < 4; ++p) acc[p] = b0;

#pragma unroll
  for (int c = 0; c < 8; ++c) {
    float w8[8];
#pragma unroll
    for (int j = 0; j < 8; ++j) w8[j] = Wo[(c * 8 + j) * HH + lane];
#pragma unroll
    for (int p = 0; p < 4; ++p) {
#pragma unroll
      for (int j = 0; j < 8; ++j) {
        float ov = ow[p * HH + c * 8 + j];   // wave-uniform -> scalar load
        acc[p] = fmaf(ov, w8[j], acc[p]);
      }
    }
  }

  float sg = ln_s[lane], bg = ln_b[lane];
  float xn[4];
#pragma unroll
  for (int p = 0; p < 4; ++p)
    xn[p] = x[(size_t)(pb + p) * HH + lane] + gelu_f(acc[p]);

  float Ts = mreduce<4>(xn, lane);
  float dd[4], sq[4];
#pragma unroll
  for (int p = 0; p < 4; ++p) {
    float mu = __shfl(Ts, p, 64) * (1.0f / HH);
    dd[p] = xn[p] - mu;
    sq[p] = dd[p] * dd[p];
  }
  float Tv = mreduce<4>(sq, lane);
  float mxp = -FLT_MAX;
#pragma unroll
  for (int p = 0; p < 4; ++p) {
    float var = __shfl(Tv, p, 64) * (1.0f / HH);
    float yv = dd[p] * rsqrtf(var + 1e-6f) * sg + bg;
    x[(size_t)(pb + p) * HH + lane] = yv;
    mxp = fmaxf(mxp, yv);
  }

  if (do_pool) {   // last layer: per-block (16-point) partial max
    red[wv][lane] = mxp;
    __syncthreads();
    if (wv == 0) {
      float m = fmaxf(fmaxf(red[0][lane], red[1][lane]),
                      fmaxf(red[2][lane], red[3][lane]));
      partial[(size_t)blockIdx.x * HH + lane] = m;
    }
  }
}

// ---------------- K6: fused pool-finish + set-encoder + final LN + max ------
__global__ __launch_bounds__(512) void k_enc(
    const float* __restrict__ partial,
    const float* __restrict__ Wek, const float* __restrict__ bek,
    const float* __restrict__ Weq, const float* __restrict__ beq,
    const float* __restrict__ Wev, const float* __restrict__ bev,
    const float* __restrict__ We1, const float* __restrict__ be1,
    const float* __restrict__ We2, const float* __restrict__ be2,
    const float* __restrict__ ln2_s, const float* __restrict__ ln2_b,
    float* __restrict__ out) {
  __shared__ float xs[8][HH], ks[8][HH], vs[8][HH], x2[8][HH];
  int b = blockIdx.x;
  int t = threadIdx.x >> 6;     // token (cloud-in-batch) 0..7
  int h = threadIdx.x & 63;
  {
    int ci = b * 8 + t;
    const float* pp = partial + (size_t)ci * 64 * HH + h;
    float mx = pp[0];
#pragma unroll
    for (int c8 = 1; c8 < 64; ++c8) mx = fmaxf(mx, pp[c8 * HH]);
    xs[t][h] = mx;
  }
  __syncthreads();

  float kk = bek[h], qq = beq[h], vv = bev[h];
#pragma unroll 8
  for (int g = 0; g < HH; ++g) {
    float xv = xs[t][g];
    kk += xv * Wek[g * HH + h];
    qq += xv * Weq[g * HH + h];
    vv += xv * Wev[g * HH + h];
  }
  ks[t][h] = kk;
  vs[t][h] = vv;
  __syncthreads();

  float logit[8];
#pragma unroll
  for (int s = 0; s < 8; ++s) {
    float tt = qq * ks[s][h];
    logit[s] = wave_sum64(tt) * 0.125f;
  }
  float m = logit[0];
#pragma unroll
  for (int s = 1; s < 8; ++s) m = fmaxf(m, logit[s]);
  float ssum = 0.f;
#pragma unroll
  for (int s = 0; s < 8; ++s) { logit[s] = expf(logit[s] - m); ssum += logit[s]; }
  float o = 0.f;
#pragma unroll
  for (int s = 0; s < 8; ++s) o += (logit[s] / ssum) * vs[s][h];

  float h1 = be1[h];
#pragma unroll 8
  for (int g = 0; g < HH; ++g) h1 += __shfl(o, g, 64) * We1[g * HH + h];
  h1 = gelu_f(h1);
  float h2 = be2[h];
#pragma unroll 8
  for (int g = 0; g < HH; ++g) h2 += __shfl(h1, g, 64) * We2[g * HH + h];

  float xn = xs[t][h] + h2;
  float mu = wave_sum64(xn) * (1.0f / HH);
  float d = xn - mu;
  float var = wave_sum64(d * d) * (1.0f / HH);
  float yv = d * rsqrtf(var + 1e-6f) * ln2_s[h] + ln2_b[h];
  x2[t][h] = yv;
  __syncthreads();
  if (t == 0) {
    float mm = x2[0][h];
#pragma unroll
    for (int s = 1; s < 8; ++s) mm = fmaxf(mm, x2[s][h]);
    out[b * HH + h] = mm;
  }
}

// ---------------------------------------------------------------------------
extern "C" void kernel_launch(void* const* d_in, const int* in_sizes, int n_in,
                              void* d_out, int out_size, void* d_ws, size_t ws_size,
                              hipStream_t stream) {
  const float* points = (const float*)d_in[0];
  const float* w_in   = (const float*)d_in[1];
  const float* b_in   = (const float*)d_in[2];
  const float* Wq     = (const float*)d_in[3];
  const float* bq     = (const float*)d_in[4];
  const float* Wk     = (const float*)d_in[5];
  const float* bk     = (const float*)d_in[6];
  const float* Wv     = (const float*)d_in[7];
  const float* bv     = (const float*)d_in[8];
  const float* Wpe    = (const float*)d_in[9];
  const float* bpe    = (const float*)d_in[10];
  const float* Wpd    = (const float*)d_in[11];
  const float* bpd    = (const float*)d_in[12];
  const float* Wa     = (const float*)d_in[13];
  const float* ba     = (const float*)d_in[14];
  const float* Wo     = (const float*)d_in[15];
  const float* bo     = (const float*)d_in[16];
  const float* ln_s   = (const float*)d_in[17];
  const float* ln_b   = (const float*)d_in[18];
  const float* Wek    = (const float*)d_in[19];
  const float* bek    = (const float*)d_in[20];
  const float* Weq    = (const float*)d_in[21];
  const float* beq    = (const float*)d_in[22];
  const float* Wev    = (const float*)d_in[23];
  const float* bev    = (const float*)d_in[24];
  const float* We1    = (const float*)d_in[25];
  const float* be1    = (const float*)d_in[26];
  const float* We2    = (const float*)d_in[27];
  const float* be2    = (const float*)d_in[28];
  const float* ln2_s  = (const float*)d_in[29];
  const float* ln2_b  = (const float*)d_in[30];

  float* ws      = (float*)d_ws;
  float* pos4    = ws;                      // 4*PTOT
  float* xbuf    = pos4 + 4 * PTOT;         // 64*PTOT
  float* qbuf    = xbuf + 64 * PTOT;        // 64*PTOT (qq, then attn-out)
  float* kkv     = qbuf + 64 * PTOT;        // 128*PTOT (kk,v interleaved)
  float* partial = kkv + 128 * PTOT;        // 2048*HH
  int*   nidx    = (int*)(partial + 2048 * HH);  // 16*PTOT ints

  k_front<<<KNN_BLKS + PTOT / 4, 256, 0, stream>>>(points, w_in, b_in,
                                                   xbuf, pos4, nidx);

  for (int l = 0; l < 3; ++l) {
    k_qkv_gemm<<<PTOT / 16, 256, 0, stream>>>(xbuf, pos4,
        Wq + l * HH * HH, bq + l * HH,
        Wk + l * HH * HH, bk + l * HH,
        Wv + l * HH * HH, bv + l * HH,
        Wpe + l * 3 * HH, bpe + l * HH,
        Wpd + l * 3 * HH, bpd + l * HH,
        qbuf, kkv);
    k_attn_core<<<PTOT / 4, 256, 0, stream>>>(qbuf, kkv, nidx, pos4,
        Wpd + l * 3 * HH, Wa + l * HH, ba + l);
    k_wo_ln<<<PTOT / 16, 256, 0, stream>>>(qbuf,
        Wo + l * HH * HH, bo + l * HH, xbuf,
        ln_s + l * HH, ln_b + l * HH, partial, l == 2 ? 1 : 0);
  }

  k_enc<<<4, 512, 0, stream>>>(partial, Wek, bek, Weq, beq, Wev, bev,
                               We1, be1, We2, be2, ln2_s, ln2_b, (float*)d_out);
}